// Round 1
// baseline (1215.575 us; speedup 1.0000x reference)
//
#include <hip/hip_runtime.h>
#include <hip/hip_bf16.h>

// chem_transformer2D: fp32-correctness baseline with flash-attention structure.
// Structure: 6 fused MLPs (12 GEMM launches) -> 2 flash-attn launches (online
// softmax over key axis, multiplicative distogram bias) -> 2 FC+ReLU+BN GEMMs.
// KQV intermediates stored bf16 in d_ws (precision budget ~1.5e-4 << 6.6e-4).

using bf16_t = __hip_bfloat16;

// ---------------- helpers ----------------
__device__ __forceinline__ unsigned int f2bfbits(float f) {
  union { float f; unsigned int i; } v; v.f = f;
  return (v.i + 0x7fffu + ((v.i >> 16) & 1u)) >> 16;  // RNE, finite inputs
}

__device__ __forceinline__ void bf16x16_to_f32(const bf16_t* __restrict__ src,
                                               float* __restrict__ dst) {
  const uint4* p = reinterpret_cast<const uint4*>(src);
  uint4 u0 = p[0];
  uint4 u1 = p[1];
  unsigned int uu[8] = {u0.x, u0.y, u0.z, u0.w, u1.x, u1.y, u1.z, u1.w};
#pragma unroll
  for (int q = 0; q < 8; ++q) {
    union { unsigned int i; float f; } lo, hi;
    lo.i = uu[q] << 16;
    hi.i = uu[q] & 0xffff0000u;
    dst[2 * q + 0] = lo.f;
    dst[2 * q + 1] = hi.f;
  }
}

// ---------------- GEMM: C[M,256] = epi(A[M,256] @ W[256,256] + bias) ----------------
enum { EPI_RELU_F32 = 0, EPI_BF16 = 1, EPI_RELU_BN = 2 };

template <int EPI>
__global__ __launch_bounds__(256, 2)
void gemm256(const float* __restrict__ A, const float* __restrict__ W,
             const float* __restrict__ bias, void* __restrict__ Cout,
             const float* __restrict__ bn_g, const float* __restrict__ bn_b,
             const float* __restrict__ bn_m, const float* __restrict__ bn_v)
{
  __shared__ float At[16][68];  // A tile transposed: At[k][i]; stride 68 (272B, 16B-aligned)
  __shared__ float Wt[16][68];  // W tile: Wt[k][n]
  const int tid = threadIdx.x;  // 256 threads = 16x16
  const int tx = tid & 15;
  const int ty = tid >> 4;
  const size_t bm = (size_t)blockIdx.x * 64;
  const int bncol = blockIdx.y * 64;

  const int ar = tid >> 2;        // A-stage row 0..63
  const int ac = (tid & 3) << 2;  // A-stage col 0,4,8,12
  const int wc = tx << 2;         // W-stage col

  float acc[4][4] = {};
  for (int k0 = 0; k0 < 256; k0 += 16) {
    float4 a4 = *reinterpret_cast<const float4*>(A + (bm + ar) * 256 + (k0 + ac));
    float4 w4 = *reinterpret_cast<const float4*>(W + (size_t)(k0 + ty) * 256 + (bncol + wc));
    At[ac + 0][ar] = a4.x;
    At[ac + 1][ar] = a4.y;
    At[ac + 2][ar] = a4.z;
    At[ac + 3][ar] = a4.w;
    *reinterpret_cast<float4*>(&Wt[ty][wc]) = w4;
    __syncthreads();
#pragma unroll
    for (int kk = 0; kk < 16; ++kk) {
      float4 av = *reinterpret_cast<const float4*>(&At[kk][ty << 2]);
      float4 wv = *reinterpret_cast<const float4*>(&Wt[kk][tx << 2]);
      const float aa[4] = {av.x, av.y, av.z, av.w};
      const float ww[4] = {wv.x, wv.y, wv.z, wv.w};
#pragma unroll
      for (int r = 0; r < 4; ++r)
#pragma unroll
        for (int c = 0; c < 4; ++c)
          acc[r][c] = fmaf(aa[r], ww[c], acc[r][c]);
    }
    __syncthreads();
  }

  const size_t row0 = bm + (ty << 2);
  const int col0 = bncol + (tx << 2);
  float bi[4], gg[4], bb[4], mm[4], iv[4];
#pragma unroll
  for (int c = 0; c < 4; ++c) bi[c] = bias[col0 + c];
  if (EPI == EPI_RELU_BN) {
#pragma unroll
    for (int c = 0; c < 4; ++c) {
      gg[c] = bn_g[col0 + c];
      bb[c] = bn_b[col0 + c];
      mm[c] = bn_m[col0 + c];
      iv[c] = rsqrtf(bn_v[col0 + c] + 1e-3f);
    }
  }
#pragma unroll
  for (int r = 0; r < 4; ++r) {
    float z[4];
#pragma unroll
    for (int c = 0; c < 4; ++c) z[c] = acc[r][c] + bi[c];
    if (EPI == EPI_RELU_F32) {
      float4 o = make_float4(fmaxf(z[0], 0.f), fmaxf(z[1], 0.f),
                             fmaxf(z[2], 0.f), fmaxf(z[3], 0.f));
      *reinterpret_cast<float4*>((float*)Cout + (row0 + r) * 256 + col0) = o;
    } else if (EPI == EPI_BF16) {
      uint2 o;
      o.x = f2bfbits(z[0]) | (f2bfbits(z[1]) << 16);
      o.y = f2bfbits(z[2]) | (f2bfbits(z[3]) << 16);
      *reinterpret_cast<uint2*>((bf16_t*)Cout + (row0 + r) * 256 + col0) = o;
    } else {
      float4 o;
      float zz[4];
#pragma unroll
      for (int c = 0; c < 4; ++c)
        zz[c] = (fmaxf(z[c], 0.f) - mm[c]) * iv[c] * gg[c] + bb[c];
      o = make_float4(zz[0], zz[1], zz[2], zz[3]);
      *reinterpret_cast<float4*>((float*)Cout + (row0 + r) * 256 + col0) = o;
    }
  }
}

// ---------------- flash attention with multiplicative distogram bias ----------------
// Out[b,i,s] = sum_j softmax_j( (Q[b,i]·K[b,j]) * bias_ij / 256 ) * V[b,j,s]
// trans=1: bias_ij = disto[b][j][i]  (dir1: i=m over L2, j=l over L1)
// trans=0: bias_ij = disto[b][i][j]  (dir2: i=l over L1, j=m over L2)
#define QB 64
#define KB 32
#define LSTR 260  // f32 words; 1040B rows, 16B-aligned; row-coeff 4 mod 32 -> <=2-way conflicts
#define PSTR 33

__global__ __launch_bounds__(256)
void attn_fused(const bf16_t* __restrict__ Q, const bf16_t* __restrict__ K,
                const bf16_t* __restrict__ V, const float* __restrict__ disto,
                float* __restrict__ Out, int trans)
{
  __shared__ float Qs[QB][LSTR];   // 66,560 B
  __shared__ float KVs[KB][LSTR];  // 33,280 B (K tile, then reused for V tile)
  __shared__ float Ps[QB][PSTR];   // 8,448 B (bias tile, overwritten in-place by P)

  const int tid = threadIdx.x;  // 256
  const int tx = tid & 15;
  const int ty = tid >> 4;      // 0..15
  const int b = blockIdx.y;
  const int i0 = blockIdx.x * QB;
  const size_t sbase = (size_t)b * (1024 * 256);
  const size_t dbase = (size_t)b * (1024 * 1024);

  // stage Q tile once (rows i0..i0+63), bf16 -> f32
#pragma unroll
  for (int it = 0; it < 4; ++it) {
    int r = ty + 16 * it;
    int c = tx * 16;
    bf16x16_to_f32(Q + sbase + (size_t)(i0 + r) * 256 + c, &Qs[r][c]);
  }

  // per-thread rows i = ty + 16*r (r=0..3); softmax state per row
  float m[4], l[4], o[4][16];
#pragma unroll
  for (int r = 0; r < 4; ++r) {
    m[r] = -1e30f;
    l[r] = 0.f;
#pragma unroll
    for (int c = 0; c < 16; ++c) o[r][c] = 0.f;
  }

  for (int j0 = 0; j0 < 1024; j0 += KB) {
    __syncthreads();  // protect prev-iter PV reads of KVs/Ps before overwrite
    // stage K tile
#pragma unroll
    for (int it = 0; it < 2; ++it) {
      int r = ty + 16 * it;
      int c = tx * 16;
      bf16x16_to_f32(K + sbase + (size_t)(j0 + r) * 256 + c, &KVs[r][c]);
    }
    // stage bias tile into Ps[i][j] (query-major in LDS for both dirs)
    if (trans) {
      int jj = tid >> 3;             // 0..31 (key row)
      int ii0 = (tid & 7) * 8;       // 0..56 (query col)
      const float* src = disto + dbase + (size_t)(j0 + jj) * 1024 + (i0 + ii0);
      float4 f0 = *reinterpret_cast<const float4*>(src);
      float4 f1 = *reinterpret_cast<const float4*>(src + 4);
      float ff[8] = {f0.x, f0.y, f0.z, f0.w, f1.x, f1.y, f1.z, f1.w};
#pragma unroll
      for (int c = 0; c < 8; ++c) Ps[ii0 + c][jj] = ff[c];
    } else {
      int ii = tid >> 2;             // 0..63 (query row)
      int jj0 = (tid & 3) * 8;       // 0..24 (key col)
      const float* src = disto + dbase + (size_t)(i0 + ii) * 1024 + (j0 + jj0);
      float4 f0 = *reinterpret_cast<const float4*>(src);
      float4 f1 = *reinterpret_cast<const float4*>(src + 4);
      float ff[8] = {f0.x, f0.y, f0.z, f0.w, f1.x, f1.y, f1.z, f1.w};
#pragma unroll
      for (int c = 0; c < 8; ++c) Ps[ii][jj0 + c] = ff[c];
    }
    __syncthreads();

    // S = Q·K^T for rows i=ty+16r, cols j=tx+16c (c=0..1)
    float s[4][2];
#pragma unroll
    for (int r = 0; r < 4; ++r) { s[r][0] = 0.f; s[r][1] = 0.f; }
    for (int d0 = 0; d0 < 256; d0 += 4) {
      float4 qv[4], kv[2];
#pragma unroll
      for (int r = 0; r < 4; ++r)
        qv[r] = *reinterpret_cast<const float4*>(&Qs[ty + 16 * r][d0]);
#pragma unroll
      for (int c = 0; c < 2; ++c)
        kv[c] = *reinterpret_cast<const float4*>(&KVs[tx + 16 * c][d0]);
#pragma unroll
      for (int r = 0; r < 4; ++r)
#pragma unroll
        for (int c = 0; c < 2; ++c) {
          s[r][c] = fmaf(qv[r].x, kv[c].x, s[r][c]);
          s[r][c] = fmaf(qv[r].y, kv[c].y, s[r][c]);
          s[r][c] = fmaf(qv[r].z, kv[c].z, s[r][c]);
          s[r][c] = fmaf(qv[r].w, kv[c].w, s[r][c]);
        }
    }

    // multiplicative bias, online softmax update (reduce across the 16-lane tx group)
    float sc_r[4];
#pragma unroll
    for (int r = 0; r < 4; ++r) {
#pragma unroll
      for (int c = 0; c < 2; ++c)
        s[r][c] *= Ps[ty + 16 * r][tx + 16 * c] * 0.00390625f;
      float mx = fmaxf(s[r][0], s[r][1]);
      mx = fmaxf(mx, __shfl_xor(mx, 1, 16));
      mx = fmaxf(mx, __shfl_xor(mx, 2, 16));
      mx = fmaxf(mx, __shfl_xor(mx, 4, 16));
      mx = fmaxf(mx, __shfl_xor(mx, 8, 16));
      float mn = fmaxf(m[r], mx);
      float sc = __expf(m[r] - mn);
      float rs = 0.f;
#pragma unroll
      for (int c = 0; c < 2; ++c) {
        float p = __expf(s[r][c] - mn);
        s[r][c] = p;
        rs += p;
      }
      rs += __shfl_xor(rs, 1, 16);
      rs += __shfl_xor(rs, 2, 16);
      rs += __shfl_xor(rs, 4, 16);
      rs += __shfl_xor(rs, 8, 16);
      l[r] = l[r] * sc + rs;
      m[r] = mn;
      sc_r[r] = sc;
      // write P in place over own bias slots (each slot touched by exactly one thread)
      Ps[ty + 16 * r][tx] = s[r][0];
      Ps[ty + 16 * r][tx + 16] = s[r][1];
    }
    __syncthreads();  // all K reads + P writes done

    // stage V over K's LDS
#pragma unroll
    for (int it = 0; it < 2; ++it) {
      int r = ty + 16 * it;
      int c = tx * 16;
      bf16x16_to_f32(V + sbase + (size_t)(j0 + r) * 256 + c, &KVs[r][c]);
    }
    // rescale accumulator while V loads are in flight
#pragma unroll
    for (int r = 0; r < 4; ++r)
#pragma unroll
      for (int c = 0; c < 16; ++c) o[r][c] *= sc_r[r];
    __syncthreads();

    // PV: o[r][qq*4+cc] covers s = 4*tx + 64*qq + cc (spread chunks -> 2-way LDS max)
    for (int j = 0; j < KB; ++j) {
      float vv[16];
#pragma unroll
      for (int qq = 0; qq < 4; ++qq) {
        float4 v4 = *reinterpret_cast<const float4*>(&KVs[j][(tx << 2) + (qq << 6)]);
        vv[qq * 4 + 0] = v4.x;
        vv[qq * 4 + 1] = v4.y;
        vv[qq * 4 + 2] = v4.z;
        vv[qq * 4 + 3] = v4.w;
      }
#pragma unroll
      for (int r = 0; r < 4; ++r) {
        const float p = Ps[ty + 16 * r][j];
#pragma unroll
        for (int c = 0; c < 16; ++c) o[r][c] = fmaf(p, vv[c], o[r][c]);
      }
    }
  }

  // normalize and write out (f32)
#pragma unroll
  for (int r = 0; r < 4; ++r) {
    const float inv = 1.0f / l[r];
    float* dst = Out + sbase + (size_t)(i0 + ty + 16 * r) * 256;
#pragma unroll
    for (int qq = 0; qq < 4; ++qq) {
      float4 w;
      w.x = o[r][qq * 4 + 0] * inv;
      w.y = o[r][qq * 4 + 1] * inv;
      w.z = o[r][qq * 4 + 2] * inv;
      w.w = o[r][qq * 4 + 3] * inv;
      *reinterpret_cast<float4*>(dst + (tx << 2) + (qq << 6)) = w;
    }
  }
}

// ---------------- launch ----------------
extern "C" void kernel_launch(void* const* d_in, const int* in_sizes, int n_in,
                              void* d_out, int out_size, void* d_ws, size_t ws_size,
                              hipStream_t stream)
{
  (void)in_sizes; (void)n_in; (void)out_size; (void)ws_size;

  const float* seq1  = (const float*)d_in[0];
  const float* seq2  = (const float*)d_in[1];
  const float* disto = (const float*)d_in[2];
  const float* kW1 = (const float*)d_in[3];
  const float* kb1 = (const float*)d_in[4];
  const float* kW2 = (const float*)d_in[5];
  const float* kb2 = (const float*)d_in[6];
  const float* qW1 = (const float*)d_in[7];
  const float* qb1 = (const float*)d_in[8];
  const float* qW2 = (const float*)d_in[9];
  const float* qb2 = (const float*)d_in[10];
  const float* vW1 = (const float*)d_in[11];
  const float* vb1 = (const float*)d_in[12];
  const float* vW2 = (const float*)d_in[13];
  const float* vb2 = (const float*)d_in[14];
  const float* fc1W = (const float*)d_in[15];
  const float* fc1b = (const float*)d_in[16];
  const float* fc2W = (const float*)d_in[17];
  const float* fc2b = (const float*)d_in[18];
  const float* bn_g = (const float*)d_in[19];
  const float* bn_b = (const float*)d_in[20];
  const float* bn_m = (const float*)d_in[21];
  const float* bn_v = (const float*)d_in[22];

  char* ws = (char*)d_ws;
  const unsigned long long BF = 8388608ull;    // one [16,1024,256] bf16 tensor
  const unsigned long long F32 = 16777216ull;  // one [16,1024,256] f32 tensor
  bf16_t* k1 = (bf16_t*)(ws + 0 * BF);
  bf16_t* q1 = (bf16_t*)(ws + 1 * BF);
  bf16_t* v1 = (bf16_t*)(ws + 2 * BF);
  bf16_t* k2 = (bf16_t*)(ws + 3 * BF);
  bf16_t* q2 = (bf16_t*)(ws + 4 * BF);
  bf16_t* v2 = (bf16_t*)(ws + 5 * BF);
  float* h   = (float*)(ws + 6 * BF);
  float* ap1 = (float*)(ws + 6 * BF + 1 * F32);
  float* ap2 = (float*)(ws + 6 * BF + 2 * F32);

  dim3 ggrid(256, 4), gblk(256);

  // 6 MLPs: h = relu(seq@W1+b1); out_bf16 = h@W2+b2
  struct MlpDesc { const float *x, *W1, *b1, *W2, *b2; bf16_t* out; };
  MlpDesc mlps[6] = {
    {seq1, kW1, kb1, kW2, kb2, k1},
    {seq1, qW1, qb1, qW2, qb2, q1},
    {seq1, vW1, vb1, vW2, vb2, v1},
    {seq2, kW1, kb1, kW2, kb2, k2},
    {seq2, qW1, qb1, qW2, qb2, q2},
    {seq2, vW1, vb1, vW2, vb2, v2},
  };
  for (int i = 0; i < 6; ++i) {
    gemm256<EPI_RELU_F32><<<ggrid, gblk, 0, stream>>>(
        mlps[i].x, mlps[i].W1, mlps[i].b1, (void*)h,
        nullptr, nullptr, nullptr, nullptr);
    gemm256<EPI_BF16><<<ggrid, gblk, 0, stream>>>(
        h, mlps[i].W2, mlps[i].b2, (void*)mlps[i].out,
        nullptr, nullptr, nullptr, nullptr);
  }

  // attention: dir1 -> ap1 (queries over L2; Q=k2,K=q1,V=v1, bias transposed)
  //            dir2 -> ap2 (queries over L1; Q=k1,K=q2,V=v2, bias direct)
  dim3 agrid(16, 16), ablk(256);
  attn_fused<<<agrid, ablk, 0, stream>>>(k2, q1, v1, disto, ap1, 1);
  attn_fused<<<agrid, ablk, 0, stream>>>(k1, q2, v2, disto, ap2, 0);

  // FC + ReLU + BN -> outputs
  float* out1 = (float*)d_out;
  float* out2 = (float*)d_out + 4194304;
  gemm256<EPI_RELU_BN><<<ggrid, gblk, 0, stream>>>(
      ap1, fc1W, fc1b, (void*)out1, bn_g, bn_b, bn_m, bn_v);
  gemm256<EPI_RELU_BN><<<ggrid, gblk, 0, stream>>>(
      ap2, fc2W, fc2b, (void*)out2, bn_g, bn_b, bn_m, bn_v);
}

// Round 2
// 493.027 us; speedup vs baseline: 2.4655x; 2.4655x over previous
//
#include <hip/hip_runtime.h>
#include <hip/hip_bf16.h>

// chem_transformer2D — round 2: full bf16 MFMA pipeline.
// pack_wt (weights -> W^T bf16) -> 12 MFMA MLP GEMMs -> 2 MFMA flash-attn
// (online softmax over key axis, multiplicative distogram bias) -> 2 FC+BN GEMMs.
// MFMA 16x16x32 bf16; C/D layout col=lane&15, row=(lane>>4)*4+reg (m89/m91).

typedef __attribute__((ext_vector_type(8))) short bf16x8;
typedef __attribute__((ext_vector_type(4))) float f32x4;
typedef unsigned short u16;

__device__ __forceinline__ unsigned int f2bfbits(float f) {
  union { float f; unsigned int i; } v; v.f = f;
  return (v.i + 0x7fffu + ((v.i >> 16) & 1u)) >> 16;  // RNE, finite inputs
}
__device__ __forceinline__ unsigned int pk2(float a, float b) {
  return f2bfbits(a) | (f2bfbits(b) << 16);
}

// ---------------- weight pack: W[256][256] f32 -> Wt[256][256] bf16 (Wt[n][k]=W[k][n]) ----
__global__ void pack_wt(const float* __restrict__ w0, const float* __restrict__ w1,
                        const float* __restrict__ w2, const float* __restrict__ w3,
                        const float* __restrict__ w4, const float* __restrict__ w5,
                        const float* __restrict__ w6, const float* __restrict__ w7,
                        u16* __restrict__ out) {
  const float* wsel[8] = {w0, w1, w2, w3, w4, w5, w6, w7};
  const float* W = wsel[blockIdx.y];
  u16* o = out + (size_t)blockIdx.y * 65536;
  int i0 = blockIdx.x * 1024 + threadIdx.x * 4;  // grid.x=64, block=256
  int n = i0 >> 8, k = i0 & 255;
  float a = W[(k + 0) * 256 + n];
  float b = W[(k + 1) * 256 + n];
  float c = W[(k + 2) * 256 + n];
  float d = W[(k + 3) * 256 + n];
  uint2 pv;
  pv.x = pk2(a, b);
  pv.y = pk2(c, d);
  *(uint2*)(o + i0) = pv;
}

// ---------------- MFMA GEMM: C[16384,256] = epi(A @ W + bias), BM=128 BN=64 BK=64 ----------
enum { EPI_RELU_BF16 = 0, EPI_BF16 = 1, EPI_VT = 2, EPI_BN = 3 };

template <bool AF32, int EPI>
__global__ __launch_bounds__(256, 2)
void gemm_mfma(const void* __restrict__ Aptr, const u16* __restrict__ Wt,
               const float* __restrict__ bias, void* __restrict__ Cout,
               const float* __restrict__ bn_g, const float* __restrict__ bn_b,
               const float* __restrict__ bn_m, const float* __restrict__ bn_v)
{
  __shared__ u16 As[128][64];  // 16KB, 16B chunks swizzled c^=(row&7)
  __shared__ u16 Ws[64][64];   // 8KB, same swizzle
  const int tid = threadIdx.x;
  const int lane = tid & 63;
  const int w = tid >> 6;
  const int wr = w >> 1, wc = w & 1;
  const int l15 = lane & 15, lq = lane >> 4;
  const size_t bm = (size_t)blockIdx.x * 128;
  const int bn = blockIdx.y * 64;

  const int sar = tid >> 1, sah = tid & 1;   // A staging: row, k-half
  const int swr = tid >> 2, swc = tid & 3;   // W staging: row, chunk-pair

  f32x4 acc[4][2];
#pragma unroll
  for (int mi = 0; mi < 4; ++mi)
#pragma unroll
    for (int ni = 0; ni < 2; ++ni) acc[mi][ni] = (f32x4)0.0f;

  for (int k0 = 0; k0 < 256; k0 += 64) {
    __syncthreads();
    if (AF32) {
      const float* A = (const float*)Aptr + (bm + sar) * 256 + k0 + sah * 32;
#pragma unroll
      for (int c = 0; c < 4; ++c) {
        float4 f0 = *(const float4*)(A + c * 8);
        float4 f1 = *(const float4*)(A + c * 8 + 4);
        uint4 pk;
        pk.x = pk2(f0.x, f0.y);
        pk.y = pk2(f0.z, f0.w);
        pk.z = pk2(f1.x, f1.y);
        pk.w = pk2(f1.z, f1.w);
        int cc = (sah * 4 + c) ^ (sar & 7);
        *(uint4*)&As[sar][cc * 8] = pk;
      }
    } else {
      const u16* A = (const u16*)Aptr + (bm + sar) * 256 + k0 + sah * 32;
#pragma unroll
      for (int c = 0; c < 4; ++c) {
        uint4 v = *(const uint4*)(A + c * 8);
        int cc = (sah * 4 + c) ^ (sar & 7);
        *(uint4*)&As[sar][cc * 8] = v;
      }
    }
    {
      const u16* Wp = Wt + (size_t)(bn + swr) * 256 + k0 + swc * 16;
#pragma unroll
      for (int c = 0; c < 2; ++c) {
        uint4 v = *(const uint4*)(Wp + c * 8);
        int cc = (swc * 2 + c) ^ (swr & 7);
        *(uint4*)&Ws[swr][cc * 8] = v;
      }
    }
    __syncthreads();
#pragma unroll
    for (int ks = 0; ks < 2; ++ks) {
      bf16x8 af[4], wf[2];
#pragma unroll
      for (int mi = 0; mi < 4; ++mi) {
        int row = wr * 64 + mi * 16 + l15;
        int cc = (ks * 4 + lq) ^ (row & 7);
        af[mi] = *(const bf16x8*)&As[row][cc * 8];
      }
#pragma unroll
      for (int ni = 0; ni < 2; ++ni) {
        int row = wc * 32 + ni * 16 + l15;
        int cc = (ks * 4 + lq) ^ (row & 7);
        wf[ni] = *(const bf16x8*)&Ws[row][cc * 8];
      }
#pragma unroll
      for (int mi = 0; mi < 4; ++mi)
#pragma unroll
        for (int ni = 0; ni < 2; ++ni)
          acc[mi][ni] = __builtin_amdgcn_mfma_f32_16x16x32_bf16(
              af[mi], wf[ni], acc[mi][ni], 0, 0, 0);
    }
  }

  // epilogue: lane's frag (mi,ni): rows bm+wr*64+mi*16+4*lq+r (r=0..3), col bn+wc*32+ni*16+l15
#pragma unroll
  for (int ni = 0; ni < 2; ++ni) {
    const int col = bn + wc * 32 + ni * 16 + l15;
    const float bi = bias[col];
    float g = 0.f, be = 0.f, mu = 0.f, iv = 0.f;
    if (EPI == EPI_BN) {
      g = bn_g[col];
      be = bn_b[col];
      mu = bn_m[col];
      iv = rsqrtf(bn_v[col] + 1e-3f);
    }
#pragma unroll
    for (int mi = 0; mi < 4; ++mi) {
      const size_t grow0 = bm + wr * 64 + mi * 16 + 4 * lq;
      float z[4];
#pragma unroll
      for (int r = 0; r < 4; ++r) z[r] = acc[mi][ni][r] + bi;
      if (EPI == EPI_RELU_BF16) {
#pragma unroll
        for (int r = 0; r < 4; ++r)
          ((u16*)Cout)[(grow0 + r) * 256 + col] = (u16)f2bfbits(fmaxf(z[r], 0.f));
      } else if (EPI == EPI_BF16) {
#pragma unroll
        for (int r = 0; r < 4; ++r)
          ((u16*)Cout)[(grow0 + r) * 256 + col] = (u16)f2bfbits(z[r]);
      } else if (EPI == EPI_VT) {
        uint2 pv;
        pv.x = pk2(z[0], z[1]);
        pv.y = pk2(z[2], z[3]);
        const size_t b = grow0 >> 10, lrow = grow0 & 1023;
        *(uint2*)((u16*)Cout + ((size_t)b * 256 + col) * 1024 + lrow) = pv;
      } else {  // EPI_BN -> f32
#pragma unroll
        for (int r = 0; r < 4; ++r) {
          float zz = fmaxf(z[r], 0.f);
          ((float*)Cout)[(grow0 + r) * 256 + col] = (zz - mu) * iv * g + be;
        }
      }
    }
  }
}

// ---------------- MFMA flash attention ----------------
// Out[b,i,s] = sum_j softmax_j( (Q[b,i]·K[b,j]) * bias_ij / 256 ) * V[j,s]
// trans=1: bias_ij = disto[b][j][i]; trans=0: bias_ij = disto[b][i][j]
// Q,K: bf16 [b][1024][256]; Vt: bf16 [b][256][1024] (pre-transposed); Out bf16.
__global__ __launch_bounds__(256, 1)
void attn_mfma(const u16* __restrict__ Q, const u16* __restrict__ K,
               const u16* __restrict__ Vt, const float* __restrict__ disto,
               u16* __restrict__ Out, int trans)
{
  __shared__ union {
    struct {
      u16 Ks[32][256];    // 16KB, chunk-swizzled c^=(row&7)
      u16 Vts[256][40];   // 20KB: 32 j bf16 + 8 pad (80B rows, 16B aligned)
      float Ps[64][33];   // 8.4KB bias tile, query-major
      u16 Pl[64][40];     // 5KB P bf16 (wave-private 16-row slabs)
    } s;
    u16 Osw[4][16][264];  // 33KB epilogue transpose (per-wave)
  } u;

  const int tid = threadIdx.x;
  const int lane = tid & 63;
  const int w = tid >> 6;
  const int l15 = lane & 15, lq = lane >> 4;
  const int b = blockIdx.y;
  const int i0 = blockIdx.x * 64;
  const size_t sbase = (size_t)b * (1024 * 256);

  // Q fragments in registers: lane covers q-row i0 + w*16 + l15, all 256 d
  bf16x8 q[8];
  {
    const u16* Qp = Q + sbase + (size_t)(i0 + w * 16 + l15) * 256 + lq * 8;
#pragma unroll
    for (int ks = 0; ks < 8; ++ks) q[ks] = *(const bf16x8*)(Qp + ks * 32);
  }

  // staged-load pointers (advance per j-tile)
  const u16* Kp = K + sbase + (size_t)(tid >> 3) * 256 + (tid & 7) * 32;
  const u16* Vp = Vt + (size_t)b * (256 * 1024) + (size_t)tid * 1024;
  const float* Dp;
  if (trans)
    Dp = disto + (size_t)b * (1024 * 1024) + (size_t)(tid >> 3) * 1024 + i0 + (tid & 7) * 8;
  else
    Dp = disto + (size_t)b * (1024 * 1024) + (size_t)(i0 + (tid >> 2)) * 1024 + (tid & 3) * 8;

  uint4 kst[4], vst[4];
  float bst[8];
  auto issue_loads = [&]() {
#pragma unroll
    for (int c = 0; c < 4; ++c) kst[c] = *(const uint4*)(Kp + c * 8);
#pragma unroll
    for (int c = 0; c < 4; ++c) vst[c] = *(const uint4*)(Vp + c * 8);
    float4 b0 = *(const float4*)(Dp);
    float4 b1 = *(const float4*)(Dp + 4);
    bst[0] = b0.x; bst[1] = b0.y; bst[2] = b0.z; bst[3] = b0.w;
    bst[4] = b1.x; bst[5] = b1.y; bst[6] = b1.z; bst[7] = b1.w;
    Kp += 32 * 256;
    Vp += 32;
    Dp += trans ? 32 * 1024 : 32;
  };
  issue_loads();  // tile 0

  float mrow[4], lrow[4];
  f32x4 o[16];
#pragma unroll
  for (int r = 0; r < 4; ++r) { mrow[r] = -1e30f; lrow[r] = 0.f; }
#pragma unroll
  for (int nt = 0; nt < 16; ++nt) o[nt] = (f32x4)0.0f;

  for (int t = 0; t < 32; ++t) {
    __syncthreads();  // previous tile fully consumed
    // LDS writes from staged regs
    {
      const int jr = tid >> 3, cg = tid & 7;
#pragma unroll
      for (int c = 0; c < 4; ++c) {
        int cc = (cg * 4 + c) ^ (jr & 7);
        *(uint4*)&u.s.Ks[jr][cc * 8] = kst[c];
      }
#pragma unroll
      for (int c = 0; c < 4; ++c) *(uint4*)&u.s.Vts[tid][c * 8] = vst[c];
      if (trans) {
        const int jj = tid >> 3, ii0 = (tid & 7) * 8;
#pragma unroll
        for (int c = 0; c < 8; ++c) u.s.Ps[ii0 + c][jj] = bst[c];
      } else {
        const int ii = tid >> 2, jj0 = (tid & 3) * 8;
#pragma unroll
        for (int c = 0; c < 8; ++c) u.s.Ps[ii][jj0 + c] = bst[c];
      }
    }
    __syncthreads();
    if (t + 1 < 32) issue_loads();  // overlap next tile's HBM latency with compute

    // QK^T: S[16 q-rows][32 keys] per wave
    f32x4 sa[2];
    sa[0] = (f32x4)0.0f;
    sa[1] = (f32x4)0.0f;
#pragma unroll
    for (int ks = 0; ks < 8; ++ks) {
#pragma unroll
      for (int nt = 0; nt < 2; ++nt) {
        int row = nt * 16 + l15;
        int cc = (ks * 4 + lq) ^ (row & 7);
        bf16x8 kb = *(const bf16x8*)&u.s.Ks[row][cc * 8];
        sa[nt] = __builtin_amdgcn_mfma_f32_16x16x32_bf16(q[ks], kb, sa[nt], 0, 0, 0);
      }
    }

    // bias * softmax (online), rows = w*16 + 4*lq + r, cols = nt*16 + l15
    float sc[4], p0v[4], p1v[4];
#pragma unroll
    for (int r = 0; r < 4; ++r) {
      const int qrow = w * 16 + 4 * lq + r;
      float s0 = sa[0][r] * u.s.Ps[qrow][l15] * 0.00390625f;
      float s1 = sa[1][r] * u.s.Ps[qrow][16 + l15] * 0.00390625f;
      float mx = fmaxf(s0, s1);
      mx = fmaxf(mx, __shfl_xor(mx, 1, 16));
      mx = fmaxf(mx, __shfl_xor(mx, 2, 16));
      mx = fmaxf(mx, __shfl_xor(mx, 4, 16));
      mx = fmaxf(mx, __shfl_xor(mx, 8, 16));
      const float mn = fmaxf(mrow[r], mx);
      const float scr = __expf(mrow[r] - mn);
      const float p0 = __expf(s0 - mn);
      const float p1 = __expf(s1 - mn);
      float rs = p0 + p1;
      rs += __shfl_xor(rs, 1, 16);
      rs += __shfl_xor(rs, 2, 16);
      rs += __shfl_xor(rs, 4, 16);
      rs += __shfl_xor(rs, 8, 16);
      lrow[r] = lrow[r] * scr + rs;
      mrow[r] = mn;
      sc[r] = scr;
      p0v[r] = p0;
      p1v[r] = p1;
    }
    // P -> wave-private LDS slab (bf16)
#pragma unroll
    for (int r = 0; r < 4; ++r) {
      const int qrow = w * 16 + 4 * lq + r;
      u.s.Pl[qrow][l15] = (u16)f2bfbits(p0v[r]);
      u.s.Pl[qrow][16 + l15] = (u16)f2bfbits(p1v[r]);
    }
    // rescale accumulator
#pragma unroll
    for (int nt = 0; nt < 16; ++nt) {
#pragma unroll
      for (int r = 0; r < 4; ++r) o[nt][r] *= sc[r];
    }
    __threadfence_block();  // wave's P writes visible to its own cross-lane reads
    const bf16x8 pa = *(const bf16x8*)&u.s.Pl[w * 16 + l15][lq * 8];
    // PV: O[16 q-rows][256 s]
#pragma unroll
    for (int nt = 0; nt < 16; ++nt) {
      bf16x8 vb = *(const bf16x8*)&u.s.Vts[nt * 16 + l15][lq * 8];
      o[nt] = __builtin_amdgcn_mfma_f32_16x16x32_bf16(pa, vb, o[nt], 0, 0, 0);
    }
  }

  // epilogue: normalize, transpose via per-wave LDS slab, coalesced bf16 store
  __syncthreads();  // all waves done reading Ks/Vts before Osw overwrite
  float inv[4];
#pragma unroll
  for (int r = 0; r < 4; ++r) inv[r] = 1.0f / lrow[r];
#pragma unroll
  for (int nt = 0; nt < 16; ++nt) {
#pragma unroll
    for (int r = 0; r < 4; ++r)
      u.Osw[w][4 * lq + r][nt * 16 + l15] = (u16)f2bfbits(o[nt][r] * inv[r]);
  }
  __threadfence_block();
  {
    const int orow = lane >> 2, och = (lane & 3) * 64;
    const u16* src = &u.Osw[w][orow][och];
    u16* dst = Out + sbase + (size_t)(i0 + w * 16 + orow) * 256 + och;
#pragma unroll
    for (int c = 0; c < 8; ++c) *(uint4*)(dst + c * 8) = *(const uint4*)(src + c * 8);
  }
}

// ---------------- launch ----------------
extern "C" void kernel_launch(void* const* d_in, const int* in_sizes, int n_in,
                              void* d_out, int out_size, void* d_ws, size_t ws_size,
                              hipStream_t stream)
{
  (void)in_sizes; (void)n_in; (void)out_size; (void)ws_size;

  const float* seq1  = (const float*)d_in[0];
  const float* seq2  = (const float*)d_in[1];
  const float* disto = (const float*)d_in[2];
  const float* kW1 = (const float*)d_in[3];
  const float* kb1 = (const float*)d_in[4];
  const float* kW2 = (const float*)d_in[5];
  const float* kb2 = (const float*)d_in[6];
  const float* qW1 = (const float*)d_in[7];
  const float* qb1 = (const float*)d_in[8];
  const float* qW2 = (const float*)d_in[9];
  const float* qb2 = (const float*)d_in[10];
  const float* vW1 = (const float*)d_in[11];
  const float* vb1 = (const float*)d_in[12];
  const float* vW2 = (const float*)d_in[13];
  const float* vb2 = (const float*)d_in[14];
  const float* fc1W = (const float*)d_in[15];
  const float* fc1b = (const float*)d_in[16];
  const float* fc2W = (const float*)d_in[17];
  const float* fc2b = (const float*)d_in[18];
  const float* bn_g = (const float*)d_in[19];
  const float* bn_b = (const float*)d_in[20];
  const float* bn_m = (const float*)d_in[21];
  const float* bn_v = (const float*)d_in[22];

  char* ws = (char*)d_ws;
  const size_t MB = 1024 * 1024;
  u16* Wt8 = (u16*)(ws);                  // 8 x 128KB = 1MB
  u16* k1  = (u16*)(ws + 1 * MB);         // each tensor: 8MB bf16 [16,1024,256]
  u16* q1  = (u16*)(ws + 9 * MB);
  u16* k2  = (u16*)(ws + 17 * MB);
  u16* q2  = (u16*)(ws + 25 * MB);
  u16* v1t = (u16*)(ws + 33 * MB);        // [16,256,1024]
  u16* v2t = (u16*)(ws + 41 * MB);
  u16* h   = (u16*)(ws + 49 * MB);
  u16* ap1 = (u16*)(ws + 57 * MB);
  u16* ap2 = (u16*)(ws + 65 * MB);

  pack_wt<<<dim3(64, 8), 256, 0, stream>>>(kW1, kW2, qW1, qW2, vW1, vW2, fc1W, fc2W, Wt8);

  dim3 ggrid(128, 4), gblk(256);
  struct Mlp { const float* x; int i1; const float* b1; int i2; const float* b2; u16* out; int vt; };
  Mlp mlps[6] = {
    {seq1, 0, kb1, 1, kb2, k1, 0},
    {seq1, 2, qb1, 3, qb2, q1, 0},
    {seq1, 4, vb1, 5, vb2, v1t, 1},
    {seq2, 0, kb1, 1, kb2, k2, 0},
    {seq2, 2, qb1, 3, qb2, q2, 0},
    {seq2, 4, vb1, 5, vb2, v2t, 1},
  };
  for (int i = 0; i < 6; ++i) {
    gemm_mfma<true, EPI_RELU_BF16><<<ggrid, gblk, 0, stream>>>(
        mlps[i].x, Wt8 + (size_t)mlps[i].i1 * 65536, mlps[i].b1, (void*)h,
        nullptr, nullptr, nullptr, nullptr);
    if (mlps[i].vt)
      gemm_mfma<false, EPI_VT><<<ggrid, gblk, 0, stream>>>(
          h, Wt8 + (size_t)mlps[i].i2 * 65536, mlps[i].b2, (void*)mlps[i].out,
          nullptr, nullptr, nullptr, nullptr);
    else
      gemm_mfma<false, EPI_BF16><<<ggrid, gblk, 0, stream>>>(
          h, Wt8 + (size_t)mlps[i].i2 * 65536, mlps[i].b2, (void*)mlps[i].out,
          nullptr, nullptr, nullptr, nullptr);
  }

  // attention: dir1 (queries over L2): Q=k2, K=q1, V=v1t, bias transposed -> ap1
  //            dir2 (queries over L1): Q=k1, K=q2, V=v2t, bias direct    -> ap2
  dim3 agrid(16, 16), ablk(256);
  attn_mfma<<<agrid, ablk, 0, stream>>>(k2, q1, v1t, disto, ap1, 1);
  attn_mfma<<<agrid, ablk, 0, stream>>>(k1, q2, v2t, disto, ap2, 0);

  // FC + ReLU + BN -> f32 outputs
  float* out1 = (float*)d_out;
  float* out2 = (float*)d_out + 4194304;
  gemm_mfma<false, EPI_BN><<<ggrid, gblk, 0, stream>>>(
      ap1, Wt8 + 6ull * 65536, fc1b, (void*)out1, bn_g, bn_b, bn_m, bn_v);
  gemm_mfma<false, EPI_BN><<<ggrid, gblk, 0, stream>>>(
      ap2, Wt8 + 7ull * 65536, fc2b, (void*)out2, bn_g, bn_b, bn_m, bn_v);
}

// Round 3
// 322.125 us; speedup vs baseline: 3.7736x; 1.5305x over previous
//
#include <hip/hip_runtime.h>
#include <hip/hip_bf16.h>

// chem_transformer2D — round 3: attn rebuilt around global_load_lds + counted
// vmcnt double-buffer (T3/T4-lite), pre-swizzled DMA sources (m173), bias in
// registers (dir1 from pre-transposed bf16 pack, dir2 from raw f32 disto).
// GEMM path unchanged from round 2 (verified).

typedef __attribute__((ext_vector_type(8))) short bf16x8;
typedef __attribute__((ext_vector_type(4))) float f32x4;
typedef unsigned short u16;

__device__ __forceinline__ unsigned int f2bfbits(float f) {
  union { float f; unsigned int i; } v; v.f = f;
  return (v.i + 0x7fffu + ((v.i >> 16) & 1u)) >> 16;  // RNE, finite inputs
}
__device__ __forceinline__ unsigned int pk2(float a, float b) {
  return f2bfbits(a) | (f2bfbits(b) << 16);
}
__device__ __forceinline__ float bf2f(u16 x) {
  union { unsigned int i; float f; } v;
  v.i = (unsigned int)x << 16;
  return v.f;
}

// ---------------- weight pack: W[256][256] f32 -> Wt[256][256] bf16 (Wt[n][k]=W[k][n]) ----
__global__ void pack_wt(const float* __restrict__ w0, const float* __restrict__ w1,
                        const float* __restrict__ w2, const float* __restrict__ w3,
                        const float* __restrict__ w4, const float* __restrict__ w5,
                        const float* __restrict__ w6, const float* __restrict__ w7,
                        u16* __restrict__ out) {
  const float* wsel[8] = {w0, w1, w2, w3, w4, w5, w6, w7};
  const float* W = wsel[blockIdx.y];
  u16* o = out + (size_t)blockIdx.y * 65536;
  int i0 = blockIdx.x * 1024 + threadIdx.x * 4;  // grid.x=64, block=256
  int n = i0 >> 8, k = i0 & 255;
  float a = W[(k + 0) * 256 + n];
  float b = W[(k + 1) * 256 + n];
  float c = W[(k + 2) * 256 + n];
  float d = W[(k + 3) * 256 + n];
  uint2 pv;
  pv.x = pk2(a, b);
  pv.y = pk2(c, d);
  *(uint2*)(o + i0) = pv;
}

// ---------------- disto pack: D1t[b][m][l] = bf16(disto[b][l][m]) ----------------
__global__ __launch_bounds__(256)
void pack_disto(const float* __restrict__ D, u16* __restrict__ Dt) {
  __shared__ u16 T[64][72];  // +8 u16 pad
  const int b = blockIdx.z, l0 = blockIdx.y * 64, m0 = blockIdx.x * 64;
  const float* src = D + (size_t)b * (1024 * 1024);
  u16* dst = Dt + (size_t)b * (1024 * 1024);
  const int r = threadIdx.x >> 2, c0 = (threadIdx.x & 3) * 16;
  float4 f[4];
#pragma unroll
  for (int q = 0; q < 4; ++q)
    f[q] = *(const float4*)(src + (size_t)(l0 + r) * 1024 + m0 + c0 + q * 4);
  uint4 p0, p1;
  p0.x = pk2(f[0].x, f[0].y); p0.y = pk2(f[0].z, f[0].w);
  p0.z = pk2(f[1].x, f[1].y); p0.w = pk2(f[1].z, f[1].w);
  p1.x = pk2(f[2].x, f[2].y); p1.y = pk2(f[2].z, f[2].w);
  p1.z = pk2(f[3].x, f[3].y); p1.w = pk2(f[3].z, f[3].w);
  *(uint4*)&T[r][c0] = p0;
  *(uint4*)&T[r][c0 + 8] = p1;
  __syncthreads();
  u16 vals[16];
#pragma unroll
  for (int k = 0; k < 16; ++k) vals[k] = T[c0 + k][r];
  *(uint4*)(dst + (size_t)(m0 + r) * 1024 + l0 + c0) = *(uint4*)&vals[0];
  *(uint4*)(dst + (size_t)(m0 + r) * 1024 + l0 + c0 + 8) = *(uint4*)&vals[8];
}

// ---------------- MFMA GEMM: C[16384,256] = epi(A @ W + bias), BM=128 BN=64 BK=64 ----------
enum { EPI_RELU_BF16 = 0, EPI_BF16 = 1, EPI_VT = 2, EPI_BN = 3 };

template <bool AF32, int EPI>
__global__ __launch_bounds__(256, 2)
void gemm_mfma(const void* __restrict__ Aptr, const u16* __restrict__ Wt,
               const float* __restrict__ bias, void* __restrict__ Cout,
               const float* __restrict__ bn_g, const float* __restrict__ bn_b,
               const float* __restrict__ bn_m, const float* __restrict__ bn_v)
{
  __shared__ u16 As[128][64];  // 16KB, 16B chunks swizzled c^=(row&7)
  __shared__ u16 Ws[64][64];   // 8KB, same swizzle
  const int tid = threadIdx.x;
  const int lane = tid & 63;
  const int w = tid >> 6;
  const int wr = w >> 1, wc = w & 1;
  const int l15 = lane & 15, lq = lane >> 4;
  const size_t bm = (size_t)blockIdx.x * 128;
  const int bn = blockIdx.y * 64;

  const int sar = tid >> 1, sah = tid & 1;   // A staging: row, k-half
  const int swr = tid >> 2, swc = tid & 3;   // W staging: row, chunk-pair

  f32x4 acc[4][2];
#pragma unroll
  for (int mi = 0; mi < 4; ++mi)
#pragma unroll
    for (int ni = 0; ni < 2; ++ni) acc[mi][ni] = (f32x4)0.0f;

  for (int k0 = 0; k0 < 256; k0 += 64) {
    __syncthreads();
    if (AF32) {
      const float* A = (const float*)Aptr + (bm + sar) * 256 + k0 + sah * 32;
#pragma unroll
      for (int c = 0; c < 4; ++c) {
        float4 f0 = *(const float4*)(A + c * 8);
        float4 f1 = *(const float4*)(A + c * 8 + 4);
        uint4 pk;
        pk.x = pk2(f0.x, f0.y);
        pk.y = pk2(f0.z, f0.w);
        pk.z = pk2(f1.x, f1.y);
        pk.w = pk2(f1.z, f1.w);
        int cc = (sah * 4 + c) ^ (sar & 7);
        *(uint4*)&As[sar][cc * 8] = pk;
      }
    } else {
      const u16* A = (const u16*)Aptr + (bm + sar) * 256 + k0 + sah * 32;
#pragma unroll
      for (int c = 0; c < 4; ++c) {
        uint4 v = *(const uint4*)(A + c * 8);
        int cc = (sah * 4 + c) ^ (sar & 7);
        *(uint4*)&As[sar][cc * 8] = v;
      }
    }
    {
      const u16* Wp = Wt + (size_t)(bn + swr) * 256 + k0 + swc * 16;
#pragma unroll
      for (int c = 0; c < 2; ++c) {
        uint4 v = *(const uint4*)(Wp + c * 8);
        int cc = (swc * 2 + c) ^ (swr & 7);
        *(uint4*)&Ws[swr][cc * 8] = v;
      }
    }
    __syncthreads();
#pragma unroll
    for (int ks = 0; ks < 2; ++ks) {
      bf16x8 af[4], wf[2];
#pragma unroll
      for (int mi = 0; mi < 4; ++mi) {
        int row = wr * 64 + mi * 16 + l15;
        int cc = (ks * 4 + lq) ^ (row & 7);
        af[mi] = *(const bf16x8*)&As[row][cc * 8];
      }
#pragma unroll
      for (int ni = 0; ni < 2; ++ni) {
        int row = wc * 32 + ni * 16 + l15;
        int cc = (ks * 4 + lq) ^ (row & 7);
        wf[ni] = *(const bf16x8*)&Ws[row][cc * 8];
      }
#pragma unroll
      for (int mi = 0; mi < 4; ++mi)
#pragma unroll
        for (int ni = 0; ni < 2; ++ni)
          acc[mi][ni] = __builtin_amdgcn_mfma_f32_16x16x32_bf16(
              af[mi], wf[ni], acc[mi][ni], 0, 0, 0);
    }
  }

  // epilogue: lane's frag (mi,ni): rows bm+wr*64+mi*16+4*lq+r (r=0..3), col bn+wc*32+ni*16+l15
#pragma unroll
  for (int ni = 0; ni < 2; ++ni) {
    const int col = bn + wc * 32 + ni * 16 + l15;
    const float bi = bias[col];
    float g = 0.f, be = 0.f, mu = 0.f, iv = 0.f;
    if (EPI == EPI_BN) {
      g = bn_g[col];
      be = bn_b[col];
      mu = bn_m[col];
      iv = rsqrtf(bn_v[col] + 1e-3f);
    }
#pragma unroll
    for (int mi = 0; mi < 4; ++mi) {
      const size_t grow0 = bm + wr * 64 + mi * 16 + 4 * lq;
      float z[4];
#pragma unroll
      for (int r = 0; r < 4; ++r) z[r] = acc[mi][ni][r] + bi;
      if (EPI == EPI_RELU_BF16) {
#pragma unroll
        for (int r = 0; r < 4; ++r)
          ((u16*)Cout)[(grow0 + r) * 256 + col] = (u16)f2bfbits(fmaxf(z[r], 0.f));
      } else if (EPI == EPI_BF16) {
#pragma unroll
        for (int r = 0; r < 4; ++r)
          ((u16*)Cout)[(grow0 + r) * 256 + col] = (u16)f2bfbits(z[r]);
      } else if (EPI == EPI_VT) {
        uint2 pv;
        pv.x = pk2(z[0], z[1]);
        pv.y = pk2(z[2], z[3]);
        const size_t b = grow0 >> 10, lrow = grow0 & 1023;
        *(uint2*)((u16*)Cout + ((size_t)b * 256 + col) * 1024 + lrow) = pv;
      } else {  // EPI_BN -> f32
#pragma unroll
        for (int r = 0; r < 4; ++r) {
          float zz = fmaxf(z[r], 0.f);
          ((float*)Cout)[(grow0 + r) * 256 + col] = (zz - mu) * iv * g + be;
        }
      }
    }
  }
}

// ---------------- MFMA flash attention (gload_lds dbuf, counted vmcnt) ----------------
// Out[b,i,s] = sum_j softmax_j( (Q[b,i]·K[b,j]) * bias_ij / 256 ) * V[j,s]
// BBF16=1: bias = D1t bf16 [b][i][j];  BBF16=0: bias = disto f32 [b][i][j].
// Q,K: bf16 [b][1024][256]; Vt: bf16 [b][256][1024]; Out bf16 [b][1024][256].
template <bool BBF16>
__global__ __launch_bounds__(256, 1)
void attn_mfma(const u16* __restrict__ Q, const u16* __restrict__ K,
               const u16* __restrict__ Vt, const void* __restrict__ Bias,
               u16* __restrict__ Out)
{
  __shared__ union U {
    struct {
      u16 Ks[2][32][256];   // 2 x 16KB, chunk-swizzle ch^(row&7)
      u16 Vts[2][256][32];  // 2 x 16KB, chunk-swizzle ch^(s&3)
      u16 Pl[64][40];       // 5KB P bf16 (wave-private 16-row slabs)
    } s;
    u16 Osw[4][16][264];    // 33KB epilogue transpose (per-wave)
  } u;

  const int tid = threadIdx.x;
  const int lane = tid & 63;
  const int w = tid >> 6;
  const int l15 = lane & 15, lq = lane >> 4;
  const int b = blockIdx.y;
  const int i0 = blockIdx.x * 64;
  const size_t sbase = (size_t)b * (1024 * 256);
  const size_t vtbase = (size_t)b * (256 * 1024);
  const size_t dbase = (size_t)b * (1024 * 1024);

  // Q fragments in registers: lane covers q-row i0 + w*16 + l15, all 256 d
  bf16x8 q[8];
  {
    const u16* Qp = Q + sbase + (size_t)(i0 + w * 16 + l15) * 256 + lq * 8;
#pragma unroll
    for (int ks = 0; ks < 8; ++ks) q[ks] = *(const bf16x8*)(Qp + ks * 32);
  }

  // DMA staging: per wave 4 K-issues + 4 V-issues of 1KB each.
  // LDS dest is linear (base + lane*16); global src is pre-swizzled (m173).
  const int cb0 = w * 4;
  auto stage = [&](int bi, int j0) {
#pragma unroll
    for (int i = 0; i < 4; ++i) {
      const int cb = cb0 + i;
      {
        const int krow = cb * 2 + (lane >> 5);
        const int kch = (lane & 31) ^ (krow & 7);
        const u16* gs = K + sbase + (size_t)(j0 + krow) * 256 + kch * 8;
        __builtin_amdgcn_global_load_lds(
            (const __attribute__((address_space(1))) unsigned int*)gs,
            (__attribute__((address_space(3))) unsigned int*)&u.s.Ks[bi][cb * 2][0],
            16, 0, 0);
      }
      {
        const int vrow = cb * 16 + (lane >> 2);
        const int vch = lane & 3;
        const u16* gs = Vt + vtbase + (size_t)vrow * 1024 + j0 + ((vch ^ (vrow & 3)) * 8);
        __builtin_amdgcn_global_load_lds(
            (const __attribute__((address_space(1))) unsigned int*)gs,
            (__attribute__((address_space(3))) unsigned int*)&u.s.Vts[bi][cb * 16][0],
            16, 0, 0);
      }
    }
  };

  float mrow[4], lrow[4];
  f32x4 o[16];
#pragma unroll
  for (int r = 0; r < 4; ++r) { mrow[r] = -1e30f; lrow[r] = 0.f; }
#pragma unroll
  for (int nt = 0; nt < 16; ++nt) o[nt] = (f32x4)0.0f;

  stage(0, 0);  // prologue: tile 0 in flight (16 VMEM/wave)

  const int vcc = lq ^ (l15 & 3);  // PV chunk swizzle (row&3 == l15&3)

  for (int t = 0; t < 32; ++t) {
    const int bi = t & 1;
    const int j0 = t * 32;

    // bias loads for tile t — issued BEFORE next stage so vmcnt(16) covers them
    float bregf[8];
    u16 bregu[8];
#pragma unroll
    for (int nt = 0; nt < 2; ++nt)
#pragma unroll
      for (int r = 0; r < 4; ++r) {
        const size_t idx = dbase + (size_t)(i0 + w * 16 + 4 * lq + r) * 1024 + j0 + l15 + 16 * nt;
        if (BBF16) bregu[nt * 4 + r] = ((const u16*)Bias)[idx];
        else bregf[nt * 4 + r] = ((const float*)Bias)[idx];
      }

    if (t + 1 < 32) {
      stage(bi ^ 1, j0 + 32);
      asm volatile("s_waitcnt vmcnt(16)" ::: "memory");  // tile t DMA + bias done; t+1 in flight
    } else {
      asm volatile("s_waitcnt vmcnt(0)" ::: "memory");
    }
    __builtin_amdgcn_s_barrier();
    __builtin_amdgcn_sched_barrier(0);

    // QK^T: S[16 q-rows][32 keys] per wave
    f32x4 sa[2];
    sa[0] = (f32x4)0.0f;
    sa[1] = (f32x4)0.0f;
#pragma unroll
    for (int ks = 0; ks < 8; ++ks)
#pragma unroll
      for (int nt = 0; nt < 2; ++nt) {
        const int row = nt * 16 + l15;
        const int cc = (ks * 4 + lq) ^ (row & 7);
        bf16x8 kb = *(const bf16x8*)&u.s.Ks[bi][row][cc * 8];
        sa[nt] = __builtin_amdgcn_mfma_f32_16x16x32_bf16(q[ks], kb, sa[nt], 0, 0, 0);
      }

    // bias * online softmax; rows = w*16 + 4*lq + r, cols = nt*16 + l15
    float sc[4], p0v[4], p1v[4];
#pragma unroll
    for (int r = 0; r < 4; ++r) {
      const float b0 = BBF16 ? bf2f(bregu[r]) : bregf[r];
      const float b1 = BBF16 ? bf2f(bregu[4 + r]) : bregf[4 + r];
      float s0 = sa[0][r] * b0 * 0.00390625f;
      float s1 = sa[1][r] * b1 * 0.00390625f;
      float mx = fmaxf(s0, s1);
      mx = fmaxf(mx, __shfl_xor(mx, 1, 16));
      mx = fmaxf(mx, __shfl_xor(mx, 2, 16));
      mx = fmaxf(mx, __shfl_xor(mx, 4, 16));
      mx = fmaxf(mx, __shfl_xor(mx, 8, 16));
      const float mn = fmaxf(mrow[r], mx);
      const float scr = __expf(mrow[r] - mn);
      const float p0 = __expf(s0 - mn);
      const float p1 = __expf(s1 - mn);
      float rs = p0 + p1;
      rs += __shfl_xor(rs, 1, 16);
      rs += __shfl_xor(rs, 2, 16);
      rs += __shfl_xor(rs, 4, 16);
      rs += __shfl_xor(rs, 8, 16);
      lrow[r] = lrow[r] * scr + rs;
      mrow[r] = mn;
      sc[r] = scr;
      p0v[r] = p0;
      p1v[r] = p1;
    }
    // P -> wave-private LDS slab (bf16)
#pragma unroll
    for (int r = 0; r < 4; ++r) {
      const int qrow = w * 16 + 4 * lq + r;
      u.s.Pl[qrow][l15] = (u16)f2bfbits(p0v[r]);
      u.s.Pl[qrow][16 + l15] = (u16)f2bfbits(p1v[r]);
    }
    // rescale accumulator
#pragma unroll
    for (int nt = 0; nt < 16; ++nt) {
#pragma unroll
      for (int r = 0; r < 4; ++r) o[nt][r] *= sc[r];
    }
    __threadfence_block();  // wave's P writes visible to its own cross-lane reads
    const bf16x8 pa = *(const bf16x8*)&u.s.Pl[w * 16 + l15][lq * 8];
    // PV: O[16 q-rows][256 s]
#pragma unroll
    for (int nt = 0; nt < 16; ++nt) {
      bf16x8 vb = *(const bf16x8*)&u.s.Vts[bi][nt * 16 + l15][vcc * 8];
      o[nt] = __builtin_amdgcn_mfma_f32_16x16x32_bf16(pa, vb, o[nt], 0, 0, 0);
    }

    asm volatile("s_waitcnt lgkmcnt(0)" ::: "memory");
    __builtin_amdgcn_s_barrier();  // all waves done reading buf[bi]
  }

  // epilogue: normalize, transpose via per-wave LDS slab, coalesced bf16 store
  float inv[4];
#pragma unroll
  for (int r = 0; r < 4; ++r) inv[r] = 1.0f / lrow[r];
#pragma unroll
  for (int nt = 0; nt < 16; ++nt) {
#pragma unroll
    for (int r = 0; r < 4; ++r)
      u.Osw[w][4 * lq + r][nt * 16 + l15] = (u16)f2bfbits(o[nt][r] * inv[r]);
  }
  __threadfence_block();
  {
    const int orow = lane >> 2, och = (lane & 3) * 64;
    const u16* src = &u.Osw[w][orow][och];
    u16* dst = Out + sbase + (size_t)(i0 + w * 16 + orow) * 256 + och;
#pragma unroll
    for (int c = 0; c < 8; ++c) *(uint4*)(dst + c * 8) = *(const uint4*)(src + c * 8);
  }
}

// ---------------- launch ----------------
extern "C" void kernel_launch(void* const* d_in, const int* in_sizes, int n_in,
                              void* d_out, int out_size, void* d_ws, size_t ws_size,
                              hipStream_t stream)
{
  (void)in_sizes; (void)n_in; (void)out_size; (void)ws_size;

  const float* seq1  = (const float*)d_in[0];
  const float* seq2  = (const float*)d_in[1];
  const float* disto = (const float*)d_in[2];
  const float* kW1 = (const float*)d_in[3];
  const float* kb1 = (const float*)d_in[4];
  const float* kW2 = (const float*)d_in[5];
  const float* kb2 = (const float*)d_in[6];
  const float* qW1 = (const float*)d_in[7];
  const float* qb1 = (const float*)d_in[8];
  const float* qW2 = (const float*)d_in[9];
  const float* qb2 = (const float*)d_in[10];
  const float* vW1 = (const float*)d_in[11];
  const float* vb1 = (const float*)d_in[12];
  const float* vW2 = (const float*)d_in[13];
  const float* vb2 = (const float*)d_in[14];
  const float* fc1W = (const float*)d_in[15];
  const float* fc1b = (const float*)d_in[16];
  const float* fc2W = (const float*)d_in[17];
  const float* fc2b = (const float*)d_in[18];
  const float* bn_g = (const float*)d_in[19];
  const float* bn_b = (const float*)d_in[20];
  const float* bn_m = (const float*)d_in[21];
  const float* bn_v = (const float*)d_in[22];

  char* ws = (char*)d_ws;
  const size_t MB = 1024 * 1024;
  u16* Wt8 = (u16*)(ws);                  // 1MB: 8 x 128KB
  u16* k1  = (u16*)(ws + 1 * MB);         // 8MB bf16 [16,1024,256] each
  u16* q1  = (u16*)(ws + 9 * MB);
  u16* k2  = (u16*)(ws + 17 * MB);
  u16* q2  = (u16*)(ws + 25 * MB);
  u16* v1t = (u16*)(ws + 33 * MB);        // [16,256,1024]
  u16* v2t = (u16*)(ws + 41 * MB);
  u16* h   = (u16*)(ws + 49 * MB);        // dead after last MLP
  u16* ap1 = (u16*)(ws + 49 * MB);        // overlays h (h consumed before attn)
  u16* ap2 = (u16*)(ws + 57 * MB);
  u16* D1t = (u16*)(ws + 65 * MB);        // 32MB bf16 [16,1024(m),1024(l)]

  pack_wt<<<dim3(64, 8), 256, 0, stream>>>(kW1, kW2, qW1, qW2, vW1, vW2, fc1W, fc2W, Wt8);
  pack_disto<<<dim3(16, 16, 16), 256, 0, stream>>>(disto, D1t);

  dim3 ggrid(128, 4), gblk(256);
  struct Mlp { const float* x; int i1; const float* b1; int i2; const float* b2; u16* out; int vt; };
  Mlp mlps[6] = {
    {seq1, 0, kb1, 1, kb2, k1, 0},
    {seq1, 2, qb1, 3, qb2, q1, 0},
    {seq1, 4, vb1, 5, vb2, v1t, 1},
    {seq2, 0, kb1, 1, kb2, k2, 0},
    {seq2, 2, qb1, 3, qb2, q2, 0},
    {seq2, 4, vb1, 5, vb2, v2t, 1},
  };
  for (int i = 0; i < 6; ++i) {
    gemm_mfma<true, EPI_RELU_BF16><<<ggrid, gblk, 0, stream>>>(
        mlps[i].x, Wt8 + (size_t)mlps[i].i1 * 65536, mlps[i].b1, (void*)h,
        nullptr, nullptr, nullptr, nullptr);
    if (mlps[i].vt)
      gemm_mfma<false, EPI_VT><<<ggrid, gblk, 0, stream>>>(
          h, Wt8 + (size_t)mlps[i].i2 * 65536, mlps[i].b2, (void*)mlps[i].out,
          nullptr, nullptr, nullptr, nullptr);
    else
      gemm_mfma<false, EPI_BF16><<<ggrid, gblk, 0, stream>>>(
          h, Wt8 + (size_t)mlps[i].i2 * 65536, mlps[i].b2, (void*)mlps[i].out,
          nullptr, nullptr, nullptr, nullptr);
  }

  // attention: dir1 (queries over L2): Q=k2, K=q1, V=v1t, bias=D1t bf16 -> ap1
  //            dir2 (queries over L1): Q=k1, K=q2, V=v2t, bias=disto f32 -> ap2
  dim3 agrid(16, 16), ablk(256);
  attn_mfma<true><<<agrid, ablk, 0, stream>>>(k2, q1, v1t, (const void*)D1t, ap1);
  attn_mfma<false><<<agrid, ablk, 0, stream>>>(k1, q2, v2t, (const void*)disto, ap2);

  // FC + ReLU + BN -> f32 outputs
  float* out1 = (float*)d_out;
  float* out2 = (float*)d_out + 4194304;
  gemm_mfma<false, EPI_BN><<<ggrid, gblk, 0, stream>>>(
      ap1, Wt8 + 6ull * 65536, fc1b, (void*)out1, bn_g, bn_b, bn_m, bn_v);
  gemm_mfma<false, EPI_BN><<<ggrid, gblk, 0, stream>>>(
      ap2, Wt8 + 7ull * 65536, fc2b, (void*)out2, bn_g, bn_b, bn_m, bn_v);
}

// Round 4
// 259.646 us; speedup vs baseline: 4.6817x; 1.2406x over previous
//
#include <hip/hip_runtime.h>
#include <hip/hip_bf16.h>

// chem_transformer2D — round 4: both attention directions fused into one
// 512-block launch (2 blocks/CU -> 2 waves/SIMD TLP) with bijective XCD
// swizzle for K/V L2 locality. Attn core = round-3 verified structure
// (global_load_lds dbuf, counted vmcnt(16), pre-swizzled DMA sources).
// GEMM path unchanged from round 2/3 (verified).

typedef __attribute__((ext_vector_type(8))) short bf16x8;
typedef __attribute__((ext_vector_type(4))) float f32x4;
typedef unsigned short u16;

__device__ __forceinline__ unsigned int f2bfbits(float f) {
  union { float f; unsigned int i; } v; v.f = f;
  return (v.i + 0x7fffu + ((v.i >> 16) & 1u)) >> 16;  // RNE, finite inputs
}
__device__ __forceinline__ unsigned int pk2(float a, float b) {
  return f2bfbits(a) | (f2bfbits(b) << 16);
}
__device__ __forceinline__ float bf2f(u16 x) {
  union { unsigned int i; float f; } v;
  v.i = (unsigned int)x << 16;
  return v.f;
}

// ---------------- weight pack: W[256][256] f32 -> Wt[256][256] bf16 (Wt[n][k]=W[k][n]) ----
__global__ void pack_wt(const float* __restrict__ w0, const float* __restrict__ w1,
                        const float* __restrict__ w2, const float* __restrict__ w3,
                        const float* __restrict__ w4, const float* __restrict__ w5,
                        const float* __restrict__ w6, const float* __restrict__ w7,
                        u16* __restrict__ out) {
  const float* wsel[8] = {w0, w1, w2, w3, w4, w5, w6, w7};
  const float* W = wsel[blockIdx.y];
  u16* o = out + (size_t)blockIdx.y * 65536;
  int i0 = blockIdx.x * 1024 + threadIdx.x * 4;  // grid.x=64, block=256
  int n = i0 >> 8, k = i0 & 255;
  float a = W[(k + 0) * 256 + n];
  float b = W[(k + 1) * 256 + n];
  float c = W[(k + 2) * 256 + n];
  float d = W[(k + 3) * 256 + n];
  uint2 pv;
  pv.x = pk2(a, b);
  pv.y = pk2(c, d);
  *(uint2*)(o + i0) = pv;
}

// ---------------- disto pack: D1t[b][m][l] = bf16(disto[b][l][m]) ----------------
__global__ __launch_bounds__(256)
void pack_disto(const float* __restrict__ D, u16* __restrict__ Dt) {
  __shared__ u16 T[64][72];  // +8 u16 pad
  const int b = blockIdx.z, l0 = blockIdx.y * 64, m0 = blockIdx.x * 64;
  const float* src = D + (size_t)b * (1024 * 1024);
  u16* dst = Dt + (size_t)b * (1024 * 1024);
  const int r = threadIdx.x >> 2, c0 = (threadIdx.x & 3) * 16;
  float4 f[4];
#pragma unroll
  for (int q = 0; q < 4; ++q)
    f[q] = *(const float4*)(src + (size_t)(l0 + r) * 1024 + m0 + c0 + q * 4);
  uint4 p0, p1;
  p0.x = pk2(f[0].x, f[0].y); p0.y = pk2(f[0].z, f[0].w);
  p0.z = pk2(f[1].x, f[1].y); p0.w = pk2(f[1].z, f[1].w);
  p1.x = pk2(f[2].x, f[2].y); p1.y = pk2(f[2].z, f[2].w);
  p1.z = pk2(f[3].x, f[3].y); p1.w = pk2(f[3].z, f[3].w);
  *(uint4*)&T[r][c0] = p0;
  *(uint4*)&T[r][c0 + 8] = p1;
  __syncthreads();
  u16 vals[16];
#pragma unroll
  for (int k = 0; k < 16; ++k) vals[k] = T[c0 + k][r];
  *(uint4*)(dst + (size_t)(m0 + r) * 1024 + l0 + c0) = *(uint4*)&vals[0];
  *(uint4*)(dst + (size_t)(m0 + r) * 1024 + l0 + c0 + 8) = *(uint4*)&vals[8];
}

// ---------------- MFMA GEMM: C[16384,256] = epi(A @ W + bias), BM=128 BN=64 BK=64 ----------
enum { EPI_RELU_BF16 = 0, EPI_BF16 = 1, EPI_VT = 2, EPI_BN = 3 };

template <bool AF32, int EPI>
__global__ __launch_bounds__(256, 2)
void gemm_mfma(const void* __restrict__ Aptr, const u16* __restrict__ Wt,
               const float* __restrict__ bias, void* __restrict__ Cout,
               const float* __restrict__ bn_g, const float* __restrict__ bn_b,
               const float* __restrict__ bn_m, const float* __restrict__ bn_v)
{
  __shared__ u16 As[128][64];  // 16KB, 16B chunks swizzled c^=(row&7)
  __shared__ u16 Ws[64][64];   // 8KB, same swizzle
  const int tid = threadIdx.x;
  const int lane = tid & 63;
  const int w = tid >> 6;
  const int wr = w >> 1, wc = w & 1;
  const int l15 = lane & 15, lq = lane >> 4;
  const size_t bm = (size_t)blockIdx.x * 128;
  const int bn = blockIdx.y * 64;

  const int sar = tid >> 1, sah = tid & 1;   // A staging: row, k-half
  const int swr = tid >> 2, swc = tid & 3;   // W staging: row, chunk-pair

  f32x4 acc[4][2];
#pragma unroll
  for (int mi = 0; mi < 4; ++mi)
#pragma unroll
    for (int ni = 0; ni < 2; ++ni) acc[mi][ni] = (f32x4)0.0f;

  for (int k0 = 0; k0 < 256; k0 += 64) {
    __syncthreads();
    if (AF32) {
      const float* A = (const float*)Aptr + (bm + sar) * 256 + k0 + sah * 32;
#pragma unroll
      for (int c = 0; c < 4; ++c) {
        float4 f0 = *(const float4*)(A + c * 8);
        float4 f1 = *(const float4*)(A + c * 8 + 4);
        uint4 pk;
        pk.x = pk2(f0.x, f0.y);
        pk.y = pk2(f0.z, f0.w);
        pk.z = pk2(f1.x, f1.y);
        pk.w = pk2(f1.z, f1.w);
        int cc = (sah * 4 + c) ^ (sar & 7);
        *(uint4*)&As[sar][cc * 8] = pk;
      }
    } else {
      const u16* A = (const u16*)Aptr + (bm + sar) * 256 + k0 + sah * 32;
#pragma unroll
      for (int c = 0; c < 4; ++c) {
        uint4 v = *(const uint4*)(A + c * 8);
        int cc = (sah * 4 + c) ^ (sar & 7);
        *(uint4*)&As[sar][cc * 8] = v;
      }
    }
    {
      const u16* Wp = Wt + (size_t)(bn + swr) * 256 + k0 + swc * 16;
#pragma unroll
      for (int c = 0; c < 2; ++c) {
        uint4 v = *(const uint4*)(Wp + c * 8);
        int cc = (swc * 2 + c) ^ (swr & 7);
        *(uint4*)&Ws[swr][cc * 8] = v;
      }
    }
    __syncthreads();
#pragma unroll
    for (int ks = 0; ks < 2; ++ks) {
      bf16x8 af[4], wf[2];
#pragma unroll
      for (int mi = 0; mi < 4; ++mi) {
        int row = wr * 64 + mi * 16 + l15;
        int cc = (ks * 4 + lq) ^ (row & 7);
        af[mi] = *(const bf16x8*)&As[row][cc * 8];
      }
#pragma unroll
      for (int ni = 0; ni < 2; ++ni) {
        int row = wc * 32 + ni * 16 + l15;
        int cc = (ks * 4 + lq) ^ (row & 7);
        wf[ni] = *(const bf16x8*)&Ws[row][cc * 8];
      }
#pragma unroll
      for (int mi = 0; mi < 4; ++mi)
#pragma unroll
        for (int ni = 0; ni < 2; ++ni)
          acc[mi][ni] = __builtin_amdgcn_mfma_f32_16x16x32_bf16(
              af[mi], wf[ni], acc[mi][ni], 0, 0, 0);
    }
  }

  // epilogue: lane's frag (mi,ni): rows bm+wr*64+mi*16+4*lq+r (r=0..3), col bn+wc*32+ni*16+l15
#pragma unroll
  for (int ni = 0; ni < 2; ++ni) {
    const int col = bn + wc * 32 + ni * 16 + l15;
    const float bi = bias[col];
    float g = 0.f, be = 0.f, mu = 0.f, iv = 0.f;
    if (EPI == EPI_BN) {
      g = bn_g[col];
      be = bn_b[col];
      mu = bn_m[col];
      iv = rsqrtf(bn_v[col] + 1e-3f);
    }
#pragma unroll
    for (int mi = 0; mi < 4; ++mi) {
      const size_t grow0 = bm + wr * 64 + mi * 16 + 4 * lq;
      float z[4];
#pragma unroll
      for (int r = 0; r < 4; ++r) z[r] = acc[mi][ni][r] + bi;
      if (EPI == EPI_RELU_BF16) {
#pragma unroll
        for (int r = 0; r < 4; ++r)
          ((u16*)Cout)[(grow0 + r) * 256 + col] = (u16)f2bfbits(fmaxf(z[r], 0.f));
      } else if (EPI == EPI_BF16) {
#pragma unroll
        for (int r = 0; r < 4; ++r)
          ((u16*)Cout)[(grow0 + r) * 256 + col] = (u16)f2bfbits(z[r]);
      } else if (EPI == EPI_VT) {
        uint2 pv;
        pv.x = pk2(z[0], z[1]);
        pv.y = pk2(z[2], z[3]);
        const size_t b = grow0 >> 10, lrow = grow0 & 1023;
        *(uint2*)((u16*)Cout + ((size_t)b * 256 + col) * 1024 + lrow) = pv;
      } else {  // EPI_BN -> f32
#pragma unroll
        for (int r = 0; r < 4; ++r) {
          float zz = fmaxf(z[r], 0.f);
          ((float*)Cout)[(grow0 + r) * 256 + col] = (zz - mu) * iv * g + be;
        }
      }
    }
  }
}

// ---------------- fused dual-direction MFMA flash attention ----------------
// 512 blocks: dir0 (Q=k2,K=q1,V=v1t,bias=D1t bf16 -> ap1) and
//             dir1 (Q=k1,K=q2,V=v2t,bias=disto f32 -> ap2), 2 blocks/CU.
// Out[b,i,s] = sum_j softmax_j( (Q[b,i]·K[b,j]) * bias[b][i][j] / 256 ) * V[j,s]
__global__ __launch_bounds__(256, 2)
void attn_mfma(const u16* __restrict__ Qa, const u16* __restrict__ Ka,
               const u16* __restrict__ Va, u16* __restrict__ OutA,
               const u16* __restrict__ Qb, const u16* __restrict__ Kb,
               const u16* __restrict__ Vb, u16* __restrict__ OutB,
               const u16* __restrict__ D1t, const float* __restrict__ D2)
{
  __shared__ union U {
    struct {
      u16 Ks[2][32][256];   // 2 x 16KB, chunk-swizzle ch^(row&7)
      u16 Vts[2][256][32];  // 2 x 16KB, chunk-swizzle ch^(s&3)
      u16 Pl[64][40];       // 5KB P bf16 (wave-private 16-row slabs)
    } s;
    u16 Osw[4][16][264];    // 33KB epilogue transpose (per-wave)
  } u;

  // bijective XCD swizzle (512 % 8 == 0): 64 consecutive logical ids / XCD,
  // so the 16 blocks sharing one (dir,b) K/V panel land on the same XCD L2.
  const int orig = blockIdx.x;
  const int lid = (orig & 7) * 64 + (orig >> 3);
  const int dir = lid >> 8;          // 0 or 1
  const int b = (lid >> 4) & 15;
  const int i0 = (lid & 15) * 64;

  const u16* __restrict__ Q = dir ? Qb : Qa;
  const u16* __restrict__ K = dir ? Kb : Ka;
  const u16* __restrict__ Vt = dir ? Vb : Va;
  u16* __restrict__ Out = dir ? OutB : OutA;

  const int tid = threadIdx.x;
  const int lane = tid & 63;
  const int w = tid >> 6;
  const int l15 = lane & 15, lq = lane >> 4;
  const size_t sbase = (size_t)b * (1024 * 256);
  const size_t vtbase = (size_t)b * (256 * 1024);
  const size_t dbase = (size_t)b * (1024 * 1024);

  // Q fragments in registers: lane covers q-row i0 + w*16 + l15, all 256 d
  bf16x8 q[8];
  {
    const u16* Qp = Q + sbase + (size_t)(i0 + w * 16 + l15) * 256 + lq * 8;
#pragma unroll
    for (int ks = 0; ks < 8; ++ks) q[ks] = *(const bf16x8*)(Qp + ks * 32);
  }

  // DMA staging: per wave 4 K-issues + 4 V-issues of 1KB each.
  // LDS dest is linear (base + lane*16); global src is pre-swizzled (m173).
  const int cb0 = w * 4;
  auto stage = [&](int bi, int j0) {
#pragma unroll
    for (int i = 0; i < 4; ++i) {
      const int cb = cb0 + i;
      {
        const int krow = cb * 2 + (lane >> 5);
        const int kch = (lane & 31) ^ (krow & 7);
        const u16* gs = K + sbase + (size_t)(j0 + krow) * 256 + kch * 8;
        __builtin_amdgcn_global_load_lds(
            (const __attribute__((address_space(1))) unsigned int*)gs,
            (__attribute__((address_space(3))) unsigned int*)&u.s.Ks[bi][cb * 2][0],
            16, 0, 0);
      }
      {
        const int vrow = cb * 16 + (lane >> 2);
        const int vch = lane & 3;
        const u16* gs = Vt + vtbase + (size_t)vrow * 1024 + j0 + ((vch ^ (vrow & 3)) * 8);
        __builtin_amdgcn_global_load_lds(
            (const __attribute__((address_space(1))) unsigned int*)gs,
            (__attribute__((address_space(3))) unsigned int*)&u.s.Vts[bi][cb * 16][0],
            16, 0, 0);
      }
    }
  };

  float mrow[4], lrow[4];
  f32x4 o[16];
#pragma unroll
  for (int r = 0; r < 4; ++r) { mrow[r] = -1e30f; lrow[r] = 0.f; }
#pragma unroll
  for (int nt = 0; nt < 16; ++nt) o[nt] = (f32x4)0.0f;

  stage(0, 0);  // prologue: tile 0 in flight (16 VMEM/wave)

  const int vcc = lq ^ (l15 & 3);  // PV chunk swizzle (row&3 == l15&3)

  for (int t = 0; t < 32; ++t) {
    const int bi = t & 1;
    const int j0 = t * 32;

    // bias loads for tile t — raw into regs, issued BEFORE next stage so
    // vmcnt(16) covers them; converted only after the wait (keeps latency hidden)
    u16 bregu[8];
    float bregf[8];
    if (dir == 0) {
#pragma unroll
      for (int nt = 0; nt < 2; ++nt)
#pragma unroll
        for (int r = 0; r < 4; ++r) {
          const size_t idx =
              dbase + (size_t)(i0 + w * 16 + 4 * lq + r) * 1024 + j0 + l15 + 16 * nt;
          bregu[nt * 4 + r] = D1t[idx];
        }
    } else {
#pragma unroll
      for (int nt = 0; nt < 2; ++nt)
#pragma unroll
        for (int r = 0; r < 4; ++r) {
          const size_t idx =
              dbase + (size_t)(i0 + w * 16 + 4 * lq + r) * 1024 + j0 + l15 + 16 * nt;
          bregf[nt * 4 + r] = D2[idx];
        }
    }

    if (t + 1 < 32) {
      stage(bi ^ 1, j0 + 32);
      asm volatile("s_waitcnt vmcnt(16)" ::: "memory");  // tile t DMA + bias done; t+1 in flight
    } else {
      asm volatile("s_waitcnt vmcnt(0)" ::: "memory");
    }
    __builtin_amdgcn_s_barrier();
    __builtin_amdgcn_sched_barrier(0);

    // QK^T: S[16 q-rows][32 keys] per wave
    f32x4 sa[2];
    sa[0] = (f32x4)0.0f;
    sa[1] = (f32x4)0.0f;
#pragma unroll
    for (int ks = 0; ks < 8; ++ks)
#pragma unroll
      for (int nt = 0; nt < 2; ++nt) {
        const int row = nt * 16 + l15;
        const int cc = (ks * 4 + lq) ^ (row & 7);
        bf16x8 kb = *(const bf16x8*)&u.s.Ks[bi][row][cc * 8];
        sa[nt] = __builtin_amdgcn_mfma_f32_16x16x32_bf16(q[ks], kb, sa[nt], 0, 0, 0);
      }

    // bias * online softmax; rows = w*16 + 4*lq + r, cols = nt*16 + l15
    float sc[4], p0v[4], p1v[4];
#pragma unroll
    for (int r = 0; r < 4; ++r) {
      float b0, b1;
      if (dir == 0) {
        b0 = bf2f(bregu[r]);
        b1 = bf2f(bregu[4 + r]);
      } else {
        b0 = bregf[r];
        b1 = bregf[4 + r];
      }
      float s0 = sa[0][r] * b0 * 0.00390625f;
      float s1 = sa[1][r] * b1 * 0.00390625f;
      float mx = fmaxf(s0, s1);
      mx = fmaxf(mx, __shfl_xor(mx, 1, 16));
      mx = fmaxf(mx, __shfl_xor(mx, 2, 16));
      mx = fmaxf(mx, __shfl_xor(mx, 4, 16));
      mx = fmaxf(mx, __shfl_xor(mx, 8, 16));
      const float mn = fmaxf(mrow[r], mx);
      const float scr = __expf(mrow[r] - mn);
      const float p0 = __expf(s0 - mn);
      const float p1 = __expf(s1 - mn);
      float rs = p0 + p1;
      rs += __shfl_xor(rs, 1, 16);
      rs += __shfl_xor(rs, 2, 16);
      rs += __shfl_xor(rs, 4, 16);
      rs += __shfl_xor(rs, 8, 16);
      lrow[r] = lrow[r] * scr + rs;
      mrow[r] = mn;
      sc[r] = scr;
      p0v[r] = p0;
      p1v[r] = p1;
    }
    // P -> wave-private LDS slab (bf16)
#pragma unroll
    for (int r = 0; r < 4; ++r) {
      const int qrow = w * 16 + 4 * lq + r;
      u.s.Pl[qrow][l15] = (u16)f2bfbits(p0v[r]);
      u.s.Pl[qrow][16 + l15] = (u16)f2bfbits(p1v[r]);
    }
    // rescale accumulator
#pragma unroll
    for (int nt = 0; nt < 16; ++nt) {
#pragma unroll
      for (int r = 0; r < 4; ++r) o[nt][r] *= sc[r];
    }
    __threadfence_block();  // wave's P writes visible to its own cross-lane reads
    const bf16x8 pa = *(const bf16x8*)&u.s.Pl[w * 16 + l15][lq * 8];
    // PV: O[16 q-rows][256 s]
#pragma unroll
    for (int nt = 0; nt < 16; ++nt) {
      bf16x8 vb = *(const bf16x8*)&u.s.Vts[bi][nt * 16 + l15][vcc * 8];
      o[nt] = __builtin_amdgcn_mfma_f32_16x16x32_bf16(pa, vb, o[nt], 0, 0, 0);
    }

    asm volatile("s_waitcnt lgkmcnt(0)" ::: "memory");
    __builtin_amdgcn_s_barrier();  // all waves done reading buf[bi]
  }

  // epilogue: normalize, transpose via per-wave LDS slab, coalesced bf16 store
  float inv[4];
#pragma unroll
  for (int r = 0; r < 4; ++r) inv[r] = 1.0f / lrow[r];
#pragma unroll
  for (int nt = 0; nt < 16; ++nt) {
#pragma unroll
    for (int r = 0; r < 4; ++r)
      u.Osw[w][4 * lq + r][nt * 16 + l15] = (u16)f2bfbits(o[nt][r] * inv[r]);
  }
  __threadfence_block();
  {
    const int orow = lane >> 2, och = (lane & 3) * 64;
    const u16* src = &u.Osw[w][orow][och];
    u16* dst = Out + sbase + (size_t)(i0 + w * 16 + orow) * 256 + och;
#pragma unroll
    for (int c = 0; c < 8; ++c) *(uint4*)(dst + c * 8) = *(const uint4*)(src + c * 8);
  }
}

// ---------------- launch ----------------
extern "C" void kernel_launch(void* const* d_in, const int* in_sizes, int n_in,
                              void* d_out, int out_size, void* d_ws, size_t ws_size,
                              hipStream_t stream)
{
  (void)in_sizes; (void)n_in; (void)out_size; (void)ws_size;

  const float* seq1  = (const float*)d_in[0];
  const float* seq2  = (const float*)d_in[1];
  const float* disto = (const float*)d_in[2];
  const float* kW1 = (const float*)d_in[3];
  const float* kb1 = (const float*)d_in[4];
  const float* kW2 = (const float*)d_in[5];
  const float* kb2 = (const float*)d_in[6];
  const float* qW1 = (const float*)d_in[7];
  const float* qb1 = (const float*)d_in[8];
  const float* qW2 = (const float*)d_in[9];
  const float* qb2 = (const float*)d_in[10];
  const float* vW1 = (const float*)d_in[11];
  const float* vb1 = (const float*)d_in[12];
  const float* vW2 = (const float*)d_in[13];
  const float* vb2 = (const float*)d_in[14];
  const float* fc1W = (const float*)d_in[15];
  const float* fc1b = (const float*)d_in[16];
  const float* fc2W = (const float*)d_in[17];
  const float* fc2b = (const float*)d_in[18];
  const float* bn_g = (const float*)d_in[19];
  const float* bn_b = (const float*)d_in[20];
  const float* bn_m = (const float*)d_in[21];
  const float* bn_v = (const float*)d_in[22];

  char* ws = (char*)d_ws;
  const size_t MB = 1024 * 1024;
  u16* Wt8 = (u16*)(ws);                  // 1MB: 8 x 128KB
  u16* k1  = (u16*)(ws + 1 * MB);         // 8MB bf16 [16,1024,256] each
  u16* q1  = (u16*)(ws + 9 * MB);
  u16* k2  = (u16*)(ws + 17 * MB);
  u16* q2  = (u16*)(ws + 25 * MB);
  u16* v1t = (u16*)(ws + 33 * MB);        // [16,256,1024]
  u16* v2t = (u16*)(ws + 41 * MB);
  u16* h   = (u16*)(ws + 49 * MB);        // dead after last MLP
  u16* ap1 = (u16*)(ws + 49 * MB);        // overlays h (h consumed before attn)
  u16* ap2 = (u16*)(ws + 57 * MB);
  u16* D1t = (u16*)(ws + 65 * MB);        // 32MB bf16 [16,1024(m),1024(l)]

  pack_wt<<<dim3(64, 8), 256, 0, stream>>>(kW1, kW2, qW1, qW2, vW1, vW2, fc1W, fc2W, Wt8);
  pack_disto<<<dim3(16, 16, 16), 256, 0, stream>>>(disto, D1t);

  dim3 ggrid(128, 4), gblk(256);
  struct Mlp { const float* x; int i1; const float* b1; int i2; const float* b2; u16* out; int vt; };
  Mlp mlps[6] = {
    {seq1, 0, kb1, 1, kb2, k1, 0},
    {seq1, 2, qb1, 3, qb2, q1, 0},
    {seq1, 4, vb1, 5, vb2, v1t, 1},
    {seq2, 0, kb1, 1, kb2, k2, 0},
    {seq2, 2, qb1, 3, qb2, q2, 0},
    {seq2, 4, vb1, 5, vb2, v2t, 1},
  };
  for (int i = 0; i < 6; ++i) {
    gemm_mfma<true, EPI_RELU_BF16><<<ggrid, gblk, 0, stream>>>(
        mlps[i].x, Wt8 + (size_t)mlps[i].i1 * 65536, mlps[i].b1, (void*)h,
        nullptr, nullptr, nullptr, nullptr);
    if (mlps[i].vt)
      gemm_mfma<false, EPI_VT><<<ggrid, gblk, 0, stream>>>(
          h, Wt8 + (size_t)mlps[i].i2 * 65536, mlps[i].b2, (void*)mlps[i].out,
          nullptr, nullptr, nullptr, nullptr);
    else
      gemm_mfma<false, EPI_BF16><<<ggrid, gblk, 0, stream>>>(
          h, Wt8 + (size_t)mlps[i].i2 * 65536, mlps[i].b2, (void*)mlps[i].out,
          nullptr, nullptr, nullptr, nullptr);
  }

  // fused attention, both directions in one 512-block launch (2 blocks/CU)
  attn_mfma<<<dim3(512), dim3(256), 0, stream>>>(
      k2, q1, v1t, ap1,        // dir0: queries over L2, bias = D1t bf16
      k1, q2, v2t, ap2,        // dir1: queries over L1, bias = disto f32
      D1t, disto);

  // FC + ReLU + BN -> f32 outputs
  float* out1 = (float*)d_out;
  float* out2 = (float*)d_out + 4194304;
  gemm_mfma<false, EPI_BN><<<ggrid, gblk, 0, stream>>>(
      ap1, Wt8 + 6ull * 65536, fc1b, (void*)out1, bn_g, bn_b, bn_m, bn_v);
  gemm_mfma<false, EPI_BN><<<ggrid, gblk, 0, stream>>>(
      ap2, Wt8 + 7ull * 65536, fc2b, (void*)out2, bn_g, bn_b, bn_m, bn_v);
}

// Round 5
// 188.484 us; speedup vs baseline: 6.4492x; 1.3775x over previous
//
#include <hip/hip_runtime.h>
#include <hip/hip_bf16.h>

// chem_transformer2D — round 5: K/Q/V MLP stacks fused into one kernel
// (12 GEMM dispatches -> 1 launch). Phase-1 computed operand-swapped
// (D[n][m]) so the H handoff through LDS is vector-write / vector-read
// with the verified ch^(row&7) chunk swizzle. attn (fused dual-dir,
// gload_lds dbuf, vmcnt(16)) and BN GEMMs unchanged from round 4.

typedef __attribute__((ext_vector_type(8))) short bf16x8;
typedef __attribute__((ext_vector_type(4))) float f32x4;
typedef unsigned short u16;

__device__ __forceinline__ unsigned int f2bfbits(float f) {
  union { float f; unsigned int i; } v; v.f = f;
  return (v.i + 0x7fffu + ((v.i >> 16) & 1u)) >> 16;  // RNE, finite inputs
}
__device__ __forceinline__ unsigned int pk2(float a, float b) {
  return f2bfbits(a) | (f2bfbits(b) << 16);
}
__device__ __forceinline__ float bf2f(u16 x) {
  union { unsigned int i; float f; } v;
  v.i = (unsigned int)x << 16;
  return v.f;
}

// ---------------- weight pack: W[256][256] f32 -> Wt[256][256] bf16 (Wt[n][k]=W[k][n]) ----
__global__ void pack_wt(const float* __restrict__ w0, const float* __restrict__ w1,
                        const float* __restrict__ w2, const float* __restrict__ w3,
                        const float* __restrict__ w4, const float* __restrict__ w5,
                        const float* __restrict__ w6, const float* __restrict__ w7,
                        u16* __restrict__ out) {
  const float* wsel[8] = {w0, w1, w2, w3, w4, w5, w6, w7};
  const float* W = wsel[blockIdx.y];
  u16* o = out + (size_t)blockIdx.y * 65536;
  int i0 = blockIdx.x * 1024 + threadIdx.x * 4;  // grid.x=64, block=256
  int n = i0 >> 8, k = i0 & 255;
  float a = W[(k + 0) * 256 + n];
  float b = W[(k + 1) * 256 + n];
  float c = W[(k + 2) * 256 + n];
  float d = W[(k + 3) * 256 + n];
  uint2 pv;
  pv.x = pk2(a, b);
  pv.y = pk2(c, d);
  *(uint2*)(o + i0) = pv;
}

// ---------------- disto pack: D1t[b][m][l] = bf16(disto[b][l][m]) ----------------
__global__ __launch_bounds__(256)
void pack_disto(const float* __restrict__ D, u16* __restrict__ Dt) {
  __shared__ u16 T[64][72];  // +8 u16 pad
  const int b = blockIdx.z, l0 = blockIdx.y * 64, m0 = blockIdx.x * 64;
  const float* src = D + (size_t)b * (1024 * 1024);
  u16* dst = Dt + (size_t)b * (1024 * 1024);
  const int r = threadIdx.x >> 2, c0 = (threadIdx.x & 3) * 16;
  float4 f[4];
#pragma unroll
  for (int q = 0; q < 4; ++q)
    f[q] = *(const float4*)(src + (size_t)(l0 + r) * 1024 + m0 + c0 + q * 4);
  uint4 p0, p1;
  p0.x = pk2(f[0].x, f[0].y); p0.y = pk2(f[0].z, f[0].w);
  p0.z = pk2(f[1].x, f[1].y); p0.w = pk2(f[1].z, f[1].w);
  p1.x = pk2(f[2].x, f[2].y); p1.y = pk2(f[2].z, f[2].w);
  p1.z = pk2(f[3].x, f[3].y); p1.w = pk2(f[3].z, f[3].w);
  *(uint4*)&T[r][c0] = p0;
  *(uint4*)&T[r][c0 + 8] = p1;
  __syncthreads();
  u16 vals[16];
#pragma unroll
  for (int k = 0; k < 16; ++k) vals[k] = T[c0 + k][r];
  *(uint4*)(dst + (size_t)(m0 + r) * 1024 + l0 + c0) = *(uint4*)&vals[0];
  *(uint4*)(dst + (size_t)(m0 + r) * 1024 + l0 + c0 + 8) = *(uint4*)&vals[8];
}

// ---------------- fused 3-MLP kernel (both layers, k/q/v, one seq tile) ----------------
// Block handles 64 rows of one sequence. Phase 1 (operand-swapped):
// D[n][m] = sum_d W1t[n][d]*A[m][d]  -> lane holds H[m=l15][n=4lq+r] -> b64 LDS write.
// Phase 2 (standard): C[m][n] from Hl b128 reads + W2t frags from L2.
__global__ __launch_bounds__(256, 2)
void mlp3_fused(const float* __restrict__ seqA, const float* __restrict__ seqB,
                const u16* __restrict__ Wt8,
                const float* __restrict__ kb1, const float* __restrict__ kb2,
                const float* __restrict__ qb1, const float* __restrict__ qb2,
                const float* __restrict__ vb1, const float* __restrict__ vb2,
                u16* __restrict__ kA, u16* __restrict__ qA, u16* __restrict__ vA,
                u16* __restrict__ kB, u16* __restrict__ qB, u16* __restrict__ vB)
{
  __shared__ u16 As[64][256];  // 32KB, chunk-swizzle ch^(row&7)
  __shared__ u16 Hl[64][256];  // 32KB, same swizzle

  const int tid = threadIdx.x;
  const int lane = tid & 63;
  const int w = tid >> 6;
  const int l15 = lane & 15, lq = lane >> 4;
  const int seqsel = blockIdx.x >> 8;
  const size_t m0 = (size_t)(blockIdx.x & 255) * 64;
  const float* __restrict__ seq = seqsel ? seqB : seqA;

  // stage A tile: seq f32 -> bf16, swizzled
  {
    const int row = tid >> 2, cg = tid & 3;
    const float* src = seq + (m0 + row) * 256 + cg * 64;
#pragma unroll
    for (int cc = 0; cc < 8; ++cc) {
      float4 f0 = *(const float4*)(src + cc * 8);
      float4 f1 = *(const float4*)(src + cc * 8 + 4);
      uint4 pk;
      pk.x = pk2(f0.x, f0.y);
      pk.y = pk2(f0.z, f0.w);
      pk.z = pk2(f1.x, f1.y);
      pk.w = pk2(f1.z, f1.w);
      const int ch = (cg * 8 + cc) ^ (row & 7);
      *(uint4*)&As[row][ch * 8] = pk;
    }
  }
  __syncthreads();

#pragma unroll
  for (int mlp = 0; mlp < 3; ++mlp) {
    const u16* __restrict__ W1 = Wt8 + (size_t)(mlp * 2) * 65536;
    const u16* __restrict__ W2 = Wt8 + (size_t)(mlp * 2 + 1) * 65536;
    const float* __restrict__ b1 = (mlp == 0) ? kb1 : (mlp == 1) ? qb1 : vb1;
    const float* __restrict__ b2 = (mlp == 0) ? kb2 : (mlp == 1) ? qb2 : vb2;
    u16* __restrict__ dst =
        (mlp == 0) ? (seqsel ? kB : kA) : (mlp == 1) ? (seqsel ? qB : qA) : (seqsel ? vB : vA);

    // bias vectors for this wave's n-block
    float b1v[4][4];
#pragma unroll
    for (int ni = 0; ni < 4; ++ni)
#pragma unroll
      for (int r = 0; r < 4; ++r) b1v[ni][r] = b1[w * 64 + ni * 16 + 4 * lq + r];
    float b2v[4];
#pragma unroll
    for (int ni = 0; ni < 4; ++ni) b2v[ni] = b2[w * 64 + ni * 16 + l15];

    // ---- phase 1: D[n][m], n in wave's 64-block, m = 0..63 ----
    f32x4 a1[4][4];
#pragma unroll
    for (int ni = 0; ni < 4; ++ni)
#pragma unroll
      for (int mj = 0; mj < 4; ++mj) a1[ni][mj] = (f32x4)0.0f;
#pragma unroll
    for (int ks = 0; ks < 8; ++ks) {
      bf16x8 wf[4], af[4];
#pragma unroll
      for (int ni = 0; ni < 4; ++ni)
        wf[ni] = *(const bf16x8*)(W1 + (size_t)(w * 64 + ni * 16 + l15) * 256 + ks * 32 + lq * 8);
#pragma unroll
      for (int mj = 0; mj < 4; ++mj) {
        const int row = mj * 16 + l15;
        const int ch = (ks * 4 + lq) ^ (row & 7);
        af[mj] = *(const bf16x8*)&As[row][ch * 8];
      }
#pragma unroll
      for (int ni = 0; ni < 4; ++ni)
#pragma unroll
        for (int mj = 0; mj < 4; ++mj)
          a1[ni][mj] = __builtin_amdgcn_mfma_f32_16x16x32_bf16(wf[ni], af[mj], a1[ni][mj], 0, 0, 0);
    }

    __syncthreads();  // prev mlp's Hl reads complete before overwrite
    // write H = relu(D^T + b1) to Hl[m][n], b64 per (ni,mj)
#pragma unroll
    for (int ni = 0; ni < 4; ++ni) {
      const int chl = w * 8 + ni * 2 + (lq >> 1);  // linear 16B-chunk index of n-group
#pragma unroll
      for (int mj = 0; mj < 4; ++mj) {
        const int m = mj * 16 + l15;
        float h0 = fmaxf(a1[ni][mj][0] + b1v[ni][0], 0.f);
        float h1 = fmaxf(a1[ni][mj][1] + b1v[ni][1], 0.f);
        float h2 = fmaxf(a1[ni][mj][2] + b1v[ni][2], 0.f);
        float h3 = fmaxf(a1[ni][mj][3] + b1v[ni][3], 0.f);
        uint2 pv;
        pv.x = pk2(h0, h1);
        pv.y = pk2(h2, h3);
        const int ch = chl ^ (m & 7);
        *(uint2*)&Hl[m][ch * 8 + (lq & 1) * 4] = pv;
      }
    }
    __syncthreads();

    // ---- phase 2: C[m][n] = Hl @ W2 + b2 ----
    f32x4 a2[4][4];
#pragma unroll
    for (int mi = 0; mi < 4; ++mi)
#pragma unroll
      for (int ni = 0; ni < 4; ++ni) a2[mi][ni] = (f32x4)0.0f;
#pragma unroll
    for (int ks = 0; ks < 8; ++ks) {
      bf16x8 wf[4], hf[4];
#pragma unroll
      for (int ni = 0; ni < 4; ++ni)
        wf[ni] = *(const bf16x8*)(W2 + (size_t)(w * 64 + ni * 16 + l15) * 256 + ks * 32 + lq * 8);
#pragma unroll
      for (int mi = 0; mi < 4; ++mi) {
        const int row = mi * 16 + l15;
        const int ch = (ks * 4 + lq) ^ (row & 7);
        hf[mi] = *(const bf16x8*)&Hl[row][ch * 8];
      }
#pragma unroll
      for (int mi = 0; mi < 4; ++mi)
#pragma unroll
        for (int ni = 0; ni < 4; ++ni)
          a2[mi][ni] = __builtin_amdgcn_mfma_f32_16x16x32_bf16(hf[mi], wf[ni], a2[mi][ni], 0, 0, 0);
    }

    // epilogue: rows m0+mi*16+4lq+r, col w*64+ni*16+l15
#pragma unroll
    for (int ni = 0; ni < 4; ++ni) {
      const int col = w * 64 + ni * 16 + l15;
      const float bb = b2v[ni];
#pragma unroll
      for (int mi = 0; mi < 4; ++mi) {
        const size_t grow0 = m0 + mi * 16 + 4 * lq;
        float z[4];
#pragma unroll
        for (int r = 0; r < 4; ++r) z[r] = a2[mi][ni][r] + bb;
        if (mlp != 2) {
#pragma unroll
          for (int r = 0; r < 4; ++r)
            dst[(grow0 + r) * 256 + col] = (u16)f2bfbits(z[r]);
        } else {  // v: transposed store vt[b][s=col][row]
          uint2 pv;
          pv.x = pk2(z[0], z[1]);
          pv.y = pk2(z[2], z[3]);
          const size_t bb2 = grow0 >> 10, lrow = grow0 & 1023;
          *(uint2*)(dst + ((size_t)bb2 * 256 + col) * 1024 + lrow) = pv;
        }
      }
    }
  }
}

// ---------------- MFMA GEMM (BN epilogue only now): C = epi(A @ W + bias) ----------
enum { EPI_RELU_BF16 = 0, EPI_BF16 = 1, EPI_VT = 2, EPI_BN = 3 };

template <bool AF32, int EPI>
__global__ __launch_bounds__(256, 2)
void gemm_mfma(const void* __restrict__ Aptr, const u16* __restrict__ Wt,
               const float* __restrict__ bias, void* __restrict__ Cout,
               const float* __restrict__ bn_g, const float* __restrict__ bn_b,
               const float* __restrict__ bn_m, const float* __restrict__ bn_v)
{
  __shared__ u16 As[128][64];  // 16KB, 16B chunks swizzled c^=(row&7)
  __shared__ u16 Ws[64][64];   // 8KB, same swizzle
  const int tid = threadIdx.x;
  const int lane = tid & 63;
  const int w = tid >> 6;
  const int wr = w >> 1, wc = w & 1;
  const int l15 = lane & 15, lq = lane >> 4;
  const size_t bm = (size_t)blockIdx.x * 128;
  const int bn = blockIdx.y * 64;

  const int sar = tid >> 1, sah = tid & 1;   // A staging: row, k-half
  const int swr = tid >> 2, swc = tid & 3;   // W staging: row, chunk-pair

  f32x4 acc[4][2];
#pragma unroll
  for (int mi = 0; mi < 4; ++mi)
#pragma unroll
    for (int ni = 0; ni < 2; ++ni) acc[mi][ni] = (f32x4)0.0f;

  for (int k0 = 0; k0 < 256; k0 += 64) {
    __syncthreads();
    if (AF32) {
      const float* A = (const float*)Aptr + (bm + sar) * 256 + k0 + sah * 32;
#pragma unroll
      for (int c = 0; c < 4; ++c) {
        float4 f0 = *(const float4*)(A + c * 8);
        float4 f1 = *(const float4*)(A + c * 8 + 4);
        uint4 pk;
        pk.x = pk2(f0.x, f0.y);
        pk.y = pk2(f0.z, f0.w);
        pk.z = pk2(f1.x, f1.y);
        pk.w = pk2(f1.z, f1.w);
        int cc = (sah * 4 + c) ^ (sar & 7);
        *(uint4*)&As[sar][cc * 8] = pk;
      }
    } else {
      const u16* A = (const u16*)Aptr + (bm + sar) * 256 + k0 + sah * 32;
#pragma unroll
      for (int c = 0; c < 4; ++c) {
        uint4 v = *(const uint4*)(A + c * 8);
        int cc = (sah * 4 + c) ^ (sar & 7);
        *(uint4*)&As[sar][cc * 8] = v;
      }
    }
    {
      const u16* Wp = Wt + (size_t)(bn + swr) * 256 + k0 + swc * 16;
#pragma unroll
      for (int c = 0; c < 2; ++c) {
        uint4 v = *(const uint4*)(Wp + c * 8);
        int cc = (swc * 2 + c) ^ (swr & 7);
        *(uint4*)&Ws[swr][cc * 8] = v;
      }
    }
    __syncthreads();
#pragma unroll
    for (int ks = 0; ks < 2; ++ks) {
      bf16x8 af[4], wf[2];
#pragma unroll
      for (int mi = 0; mi < 4; ++mi) {
        int row = wr * 64 + mi * 16 + l15;
        int cc = (ks * 4 + lq) ^ (row & 7);
        af[mi] = *(const bf16x8*)&As[row][cc * 8];
      }
#pragma unroll
      for (int ni = 0; ni < 2; ++ni) {
        int row = wc * 32 + ni * 16 + l15;
        int cc = (ks * 4 + lq) ^ (row & 7);
        wf[ni] = *(const bf16x8*)&Ws[row][cc * 8];
      }
#pragma unroll
      for (int mi = 0; mi < 4; ++mi)
#pragma unroll
        for (int ni = 0; ni < 2; ++ni)
          acc[mi][ni] = __builtin_amdgcn_mfma_f32_16x16x32_bf16(
              af[mi], wf[ni], acc[mi][ni], 0, 0, 0);
    }
  }

#pragma unroll
  for (int ni = 0; ni < 2; ++ni) {
    const int col = bn + wc * 32 + ni * 16 + l15;
    const float bi = bias[col];
    float g = 0.f, be = 0.f, mu = 0.f, iv = 0.f;
    if (EPI == EPI_BN) {
      g = bn_g[col];
      be = bn_b[col];
      mu = bn_m[col];
      iv = rsqrtf(bn_v[col] + 1e-3f);
    }
#pragma unroll
    for (int mi = 0; mi < 4; ++mi) {
      const size_t grow0 = bm + wr * 64 + mi * 16 + 4 * lq;
      float z[4];
#pragma unroll
      for (int r = 0; r < 4; ++r) z[r] = acc[mi][ni][r] + bi;
      if (EPI == EPI_RELU_BF16) {
#pragma unroll
        for (int r = 0; r < 4; ++r)
          ((u16*)Cout)[(grow0 + r) * 256 + col] = (u16)f2bfbits(fmaxf(z[r], 0.f));
      } else if (EPI == EPI_BF16) {
#pragma unroll
        for (int r = 0; r < 4; ++r)
          ((u16*)Cout)[(grow0 + r) * 256 + col] = (u16)f2bfbits(z[r]);
      } else if (EPI == EPI_VT) {
        uint2 pv;
        pv.x = pk2(z[0], z[1]);
        pv.y = pk2(z[2], z[3]);
        const size_t b = grow0 >> 10, lrow = grow0 & 1023;
        *(uint2*)((u16*)Cout + ((size_t)b * 256 + col) * 1024 + lrow) = pv;
      } else {  // EPI_BN -> f32
#pragma unroll
        for (int r = 0; r < 4; ++r) {
          float zz = fmaxf(z[r], 0.f);
          ((float*)Cout)[(grow0 + r) * 256 + col] = (zz - mu) * iv * g + be;
        }
      }
    }
  }
}

// ---------------- fused dual-direction MFMA flash attention (round-4 verified) ----------------
__global__ __launch_bounds__(256, 2)
void attn_mfma(const u16* __restrict__ Qa, const u16* __restrict__ Ka,
               const u16* __restrict__ Va, u16* __restrict__ OutA,
               const u16* __restrict__ Qb, const u16* __restrict__ Kb,
               const u16* __restrict__ Vb, u16* __restrict__ OutB,
               const u16* __restrict__ D1t, const float* __restrict__ D2)
{
  __shared__ union U {
    struct {
      u16 Ks[2][32][256];   // 2 x 16KB, chunk-swizzle ch^(row&7)
      u16 Vts[2][256][32];  // 2 x 16KB, chunk-swizzle ch^(s&3)
      u16 Pl[64][40];       // 5KB P bf16 (wave-private 16-row slabs)
    } s;
    u16 Osw[4][16][264];    // 33KB epilogue transpose (per-wave)
  } u;

  const int orig = blockIdx.x;
  const int lid = (orig & 7) * 64 + (orig >> 3);
  const int dir = lid >> 8;
  const int b = (lid >> 4) & 15;
  const int i0 = (lid & 15) * 64;

  const u16* __restrict__ Q = dir ? Qb : Qa;
  const u16* __restrict__ K = dir ? Kb : Ka;
  const u16* __restrict__ Vt = dir ? Vb : Va;
  u16* __restrict__ Out = dir ? OutB : OutA;

  const int tid = threadIdx.x;
  const int lane = tid & 63;
  const int w = tid >> 6;
  const int l15 = lane & 15, lq = lane >> 4;
  const size_t sbase = (size_t)b * (1024 * 256);
  const size_t vtbase = (size_t)b * (256 * 1024);
  const size_t dbase = (size_t)b * (1024 * 1024);

  bf16x8 q[8];
  {
    const u16* Qp = Q + sbase + (size_t)(i0 + w * 16 + l15) * 256 + lq * 8;
#pragma unroll
    for (int ks = 0; ks < 8; ++ks) q[ks] = *(const bf16x8*)(Qp + ks * 32);
  }

  const int cb0 = w * 4;
  auto stage = [&](int bi, int j0) {
#pragma unroll
    for (int i = 0; i < 4; ++i) {
      const int cb = cb0 + i;
      {
        const int krow = cb * 2 + (lane >> 5);
        const int kch = (lane & 31) ^ (krow & 7);
        const u16* gs = K + sbase + (size_t)(j0 + krow) * 256 + kch * 8;
        __builtin_amdgcn_global_load_lds(
            (const __attribute__((address_space(1))) unsigned int*)gs,
            (__attribute__((address_space(3))) unsigned int*)&u.s.Ks[bi][cb * 2][0],
            16, 0, 0);
      }
      {
        const int vrow = cb * 16 + (lane >> 2);
        const int vch = lane & 3;
        const u16* gs = Vt + vtbase + (size_t)vrow * 1024 + j0 + ((vch ^ (vrow & 3)) * 8);
        __builtin_amdgcn_global_load_lds(
            (const __attribute__((address_space(1))) unsigned int*)gs,
            (__attribute__((address_space(3))) unsigned int*)&u.s.Vts[bi][cb * 16][0],
            16, 0, 0);
      }
    }
  };

  float mrow[4], lrow[4];
  f32x4 o[16];
#pragma unroll
  for (int r = 0; r < 4; ++r) { mrow[r] = -1e30f; lrow[r] = 0.f; }
#pragma unroll
  for (int nt = 0; nt < 16; ++nt) o[nt] = (f32x4)0.0f;

  stage(0, 0);

  const int vcc = lq ^ (l15 & 3);

  for (int t = 0; t < 32; ++t) {
    const int bi = t & 1;
    const int j0 = t * 32;

    u16 bregu[8];
    float bregf[8];
    if (dir == 0) {
#pragma unroll
      for (int nt = 0; nt < 2; ++nt)
#pragma unroll
        for (int r = 0; r < 4; ++r) {
          const size_t idx =
              dbase + (size_t)(i0 + w * 16 + 4 * lq + r) * 1024 + j0 + l15 + 16 * nt;
          bregu[nt * 4 + r] = D1t[idx];
        }
    } else {
#pragma unroll
      for (int nt = 0; nt < 2; ++nt)
#pragma unroll
        for (int r = 0; r < 4; ++r) {
          const size_t idx =
              dbase + (size_t)(i0 + w * 16 + 4 * lq + r) * 1024 + j0 + l15 + 16 * nt;
          bregf[nt * 4 + r] = D2[idx];
        }
    }

    if (t + 1 < 32) {
      stage(bi ^ 1, j0 + 32);
      asm volatile("s_waitcnt vmcnt(16)" ::: "memory");
    } else {
      asm volatile("s_waitcnt vmcnt(0)" ::: "memory");
    }
    __builtin_amdgcn_s_barrier();
    __builtin_amdgcn_sched_barrier(0);

    f32x4 sa[2];
    sa[0] = (f32x4)0.0f;
    sa[1] = (f32x4)0.0f;
#pragma unroll
    for (int ks = 0; ks < 8; ++ks)
#pragma unroll
      for (int nt = 0; nt < 2; ++nt) {
        const int row = nt * 16 + l15;
        const int cc = (ks * 4 + lq) ^ (row & 7);
        bf16x8 kb = *(const bf16x8*)&u.s.Ks[bi][row][cc * 8];
        sa[nt] = __builtin_amdgcn_mfma_f32_16x16x32_bf16(q[ks], kb, sa[nt], 0, 0, 0);
      }

    float sc[4], p0v[4], p1v[4];
#pragma unroll
    for (int r = 0; r < 4; ++r) {
      float b0, b1;
      if (dir == 0) {
        b0 = bf2f(bregu[r]);
        b1 = bf2f(bregu[4 + r]);
      } else {
        b0 = bregf[r];
        b1 = bregf[4 + r];
      }
      float s0 = sa[0][r] * b0 * 0.00390625f;
      float s1 = sa[1][r] * b1 * 0.00390625f;
      float mx = fmaxf(s0, s1);
      mx = fmaxf(mx, __shfl_xor(mx, 1, 16));
      mx = fmaxf(mx, __shfl_xor(mx, 2, 16));
      mx = fmaxf(mx, __shfl_xor(mx, 4, 16));
      mx = fmaxf(mx, __shfl_xor(mx, 8, 16));
      const float mn = fmaxf(mrow[r], mx);
      const float scr = __expf(mrow[r] - mn);
      const float p0 = __expf(s0 - mn);
      const float p1 = __expf(s1 - mn);
      float rs = p0 + p1;
      rs += __shfl_xor(rs, 1, 16);
      rs += __shfl_xor(rs, 2, 16);
      rs += __shfl_xor(rs, 4, 16);
      rs += __shfl_xor(rs, 8, 16);
      lrow[r] = lrow[r] * scr + rs;
      mrow[r] = mn;
      sc[r] = scr;
      p0v[r] = p0;
      p1v[r] = p1;
    }
#pragma unroll
    for (int r = 0; r < 4; ++r) {
      const int qrow = w * 16 + 4 * lq + r;
      u.s.Pl[qrow][l15] = (u16)f2bfbits(p0v[r]);
      u.s.Pl[qrow][16 + l15] = (u16)f2bfbits(p1v[r]);
    }
#pragma unroll
    for (int nt = 0; nt < 16; ++nt) {
#pragma unroll
      for (int r = 0; r < 4; ++r) o[nt][r] *= sc[r];
    }
    __threadfence_block();
    const bf16x8 pa = *(const bf16x8*)&u.s.Pl[w * 16 + l15][lq * 8];
#pragma unroll
    for (int nt = 0; nt < 16; ++nt) {
      bf16x8 vb = *(const bf16x8*)&u.s.Vts[bi][nt * 16 + l15][vcc * 8];
      o[nt] = __builtin_amdgcn_mfma_f32_16x16x32_bf16(pa, vb, o[nt], 0, 0, 0);
    }

    asm volatile("s_waitcnt lgkmcnt(0)" ::: "memory");
    __builtin_amdgcn_s_barrier();
  }

  float inv[4];
#pragma unroll
  for (int r = 0; r < 4; ++r) inv[r] = 1.0f / lrow[r];
#pragma unroll
  for (int nt = 0; nt < 16; ++nt) {
#pragma unroll
    for (int r = 0; r < 4; ++r)
      u.Osw[w][4 * lq + r][nt * 16 + l15] = (u16)f2bfbits(o[nt][r] * inv[r]);
  }
  __threadfence_block();
  {
    const int orow = lane >> 2, och = (lane & 3) * 64;
    const u16* src = &u.Osw[w][orow][och];
    u16* dst = Out + sbase + (size_t)(i0 + w * 16 + orow) * 256 + och;
#pragma unroll
    for (int c = 0; c < 8; ++c) *(uint4*)(dst + c * 8) = *(const uint4*)(src + c * 8);
  }
}

// ---------------- launch ----------------
extern "C" void kernel_launch(void* const* d_in, const int* in_sizes, int n_in,
                              void* d_out, int out_size, void* d_ws, size_t ws_size,
                              hipStream_t stream)
{
  (void)in_sizes; (void)n_in; (void)out_size; (void)ws_size;

  const float* seq1  = (const float*)d_in[0];
  const float* seq2  = (const float*)d_in[1];
  const float* disto = (const float*)d_in[2];
  const float* kW1 = (const float*)d_in[3];
  const float* kb1 = (const float*)d_in[4];
  const float* kW2 = (const float*)d_in[5];
  const float* kb2 = (const float*)d_in[6];
  const float* qW1 = (const float*)d_in[7];
  const float* qb1 = (const float*)d_in[8];
  const float* qW2 = (const float*)d_in[9];
  const float* qb2 = (const float*)d_in[10];
  const float* vW1 = (const float*)d_in[11];
  const float* vb1 = (const float*)d_in[12];
  const float* vW2 = (const float*)d_in[13];
  const float* vb2 = (const float*)d_in[14];
  const float* fc1W = (const float*)d_in[15];
  const float* fc1b = (const float*)d_in[16];
  const float* fc2W = (const float*)d_in[17];
  const float* fc2b = (const float*)d_in[18];
  const float* bn_g = (const float*)d_in[19];
  const float* bn_b = (const float*)d_in[20];
  const float* bn_m = (const float*)d_in[21];
  const float* bn_v = (const float*)d_in[22];

  char* ws = (char*)d_ws;
  const size_t MB = 1024 * 1024;
  u16* Wt8 = (u16*)(ws);                  // 1MB: 8 x 128KB
  u16* k1  = (u16*)(ws + 1 * MB);         // 8MB bf16 [16,1024,256] each
  u16* q1  = (u16*)(ws + 9 * MB);
  u16* k2  = (u16*)(ws + 17 * MB);
  u16* q2  = (u16*)(ws + 25 * MB);
  u16* v1t = (u16*)(ws + 33 * MB);        // [16,256,1024]
  u16* v2t = (u16*)(ws + 41 * MB);
  u16* ap1 = (u16*)(ws + 49 * MB);
  u16* ap2 = (u16*)(ws + 57 * MB);
  u16* D1t = (u16*)(ws + 65 * MB);        // 32MB bf16 [16,1024(m),1024(l)]

  pack_wt<<<dim3(64, 8), 256, 0, stream>>>(kW1, kW2, qW1, qW2, vW1, vW2, fc1W, fc2W, Wt8);
  pack_disto<<<dim3(16, 16, 16), 256, 0, stream>>>(disto, D1t);

  // all 6 MLPs (both layers) in one launch: blocks 0..255 -> seq1, 256..511 -> seq2
  mlp3_fused<<<dim3(512), dim3(256), 0, stream>>>(
      seq1, seq2, Wt8, kb1, kb2, qb1, qb2, vb1, vb2,
      k1, q1, v1t, k2, q2, v2t);

  // fused attention, both directions in one 512-block launch (2 blocks/CU)
  attn_mfma<<<dim3(512), dim3(256), 0, stream>>>(
      k2, q1, v1t, ap1,        // dir0: queries over L2, bias = D1t bf16
      k1, q2, v2t, ap2,        // dir1: queries over L1, bias = disto f32
      D1t, disto);

  // FC + ReLU + BN -> f32 outputs
  float* out1 = (float*)d_out;
  float* out2 = (float*)d_out + 4194304;
  dim3 ggrid(128, 4), gblk(256);
  gemm_mfma<false, EPI_BN><<<ggrid, gblk, 0, stream>>>(
      ap1, Wt8 + 6ull * 65536, fc1b, (void*)out1, bn_g, bn_b, bn_m, bn_v);
  gemm_mfma<false, EPI_BN><<<ggrid, gblk, 0, stream>>>(
      ap2, Wt8 + 7ull * 65536, fc2b, (void*)out2, bn_g, bn_b, bn_m, bn_v);
}